// Round 1
// baseline (20605.943 us; speedup 1.0000x reference)
//
#include <hip/hip_runtime.h>
#include <math.h>

#define NBLK 64
#define NTHR 512
#define HD   512
#define NMAX 128
#define LSEQ 1024

// ---------------- helpers ----------------
__device__ __forceinline__ float bf2f(unsigned short u){
  union { unsigned int i; float f; } v; v.i = ((unsigned int)u) << 16; return v.f;
}
__device__ __forceinline__ unsigned short f2bf(float f){
  union { float f; unsigned int i; } v; v.f = f;
  unsigned int x = v.i;
  return (unsigned short)((x + 0x7fffu + ((x >> 16) & 1u)) >> 16);
}
__device__ __forceinline__ float wred(float a){
  #pragma unroll
  for (int off = 32; off; off >>= 1) a += __shfl_xor(a, off);
  return a;
}
__device__ __forceinline__ float wredmax(float a){
  #pragma unroll
  for (int off = 32; off; off >>= 1) a = fmaxf(a, __shfl_xor(a, off));
  return a;
}
// bf16 LDS row (len 512) dot fp32 LDS vector
__device__ __forceinline__ float dot512(const unsigned short* w, const float* x, int lane){
  float acc = 0.f;
  #pragma unroll
  for (int k = 0; k < 8; ++k){ int j = lane + (k << 6); acc += bf2f(w[j]) * x[j]; }
  return wred(acc);
}
// bf16 LDS row (len 1024) dot [x ; y]
__device__ __forceinline__ float dot1024(const unsigned short* w, const float* x, const float* y, int lane){
  float acc = 0.f;
  #pragma unroll
  for (int k = 0; k < 8; ++k){ int j = lane + (k << 6); acc += bf2f(w[j]) * x[j]; }
  #pragma unroll
  for (int k = 0; k < 8; ++k){ int j = lane + (k << 6); acc += bf2f(w[512 + j]) * y[j]; }
  return wred(acc);
}
// fp32 global row dot fp32 LDS vector
__device__ __forceinline__ float dot512g(const float* __restrict__ w, const float* x, int lane){
  float acc = 0.f;
  #pragma unroll
  for (int k = 0; k < 8; ++k){ int j = lane + (k << 6); acc += w[j] * x[j]; }
  return wred(acc);
}
__device__ __forceinline__ float sigm(float x){ return 1.f / (1.f + __expf(-x)); }

// flag-based grid barrier: blocks 1..63 set flags[b]=target; block 0 wave 0
// polls them then publishes go=target. Monotone targets -> no reset needed.
__device__ __forceinline__ void gbar(int* flags, int* go, int target){
  __threadfence();
  __syncthreads();
  if (blockIdx.x == 0){
    int i = threadIdx.x;
    if (i > 0 && i < NBLK){
      while (__hip_atomic_load(&flags[i], __ATOMIC_RELAXED, __HIP_MEMORY_SCOPE_AGENT) < target) {}
    }
    __threadfence();
    if (i == 0) __hip_atomic_store(go, target, __ATOMIC_RELEASE, __HIP_MEMORY_SCOPE_AGENT);
  } else {
    if (threadIdx.x == 0){
      __hip_atomic_store(&flags[blockIdx.x], target, __ATOMIC_RELEASE, __HIP_MEMORY_SCOPE_AGENT);
      while (__hip_atomic_load(go, __ATOMIC_RELAXED, __HIP_MEMORY_SCOPE_AGENT) < target) {}
    }
  }
  __syncthreads();
  __threadfence();
}

// pending scalar log-softmax work, executed by block 0, wave 7 only.
// pend: 0 none, 1 add_edge(idx 0), 2 stop_edge(idx 1), 3 choose_dest
__device__ __forceinline__ void run_pend(int pend, int pcur, int parg,
    const float* epart, const float* logits, const float* s_be2, float* s_nll, int lane){
  if (pend == 1 || pend == 2){
    float p0 = wred(epart[lane]);
    float p1 = wred(epart[64 + lane]);
    if (lane == 0){
      float l0 = p0 + s_be2[0], l1 = p1 + s_be2[1];
      float m = fmaxf(l0, l1);
      float lse = m + logf(__expf(l0 - m) + __expf(l1 - m));
      s_nll[0] += lse - ((pend == 1) ? l0 : l1);
    }
  } else if (pend == 3){
    float x0 = (lane < pcur)      ? logits[lane]      : -INFINITY;
    float x1 = (lane + 64 < pcur) ? logits[lane + 64] : -INFINITY;
    float m = wredmax(fmaxf(x0, x1));
    float s = wred(__expf(x0 - m) + __expf(x1 - m));   // exp(-inf - m) == 0
    float la = (parg < 64) ? __shfl(x0, parg) : __shfl(x1, parg - 64);
    if (lane == 0) s_nll[0] += (m + logf(s)) - la;
  }
}

#define SMEM_BYTES (4*24*512*2 + 2*8*1024*2 + 4*(3*512 + 24*5 + 8 + 8 + 16 + 2 + 16 + 1))

__global__ void __launch_bounds__(NTHR, 1)
dgmg_kernel(const int* __restrict__ actions, const int* __restrict__ argseq,
            const float* __restrict__ node_init, const float* __restrict__ w_nip, const float* __restrict__ b_nip,
            const float* __restrict__ w_e1, const float* __restrict__ b_e1,
            const float* __restrict__ w_e2, const float* __restrict__ b_e2,
            const float* __restrict__ w_q, const float* __restrict__ b_q,
            const float* __restrict__ w_k,
            const float* __restrict__ wih_n, const float* __restrict__ whh_n,
            const float* __restrict__ bih_n, const float* __restrict__ bhh_n,
            const float* __restrict__ wih_g, const float* __restrict__ whh_g,
            const float* __restrict__ bih_g, const float* __restrict__ bhh_g,
            const float* __restrict__ graph0,
            float* __restrict__ out, unsigned char* __restrict__ ws)
{
  extern __shared__ unsigned char smem[];
  unsigned short* s_wihg = (unsigned short*)smem;        // [24][512]
  unsigned short* s_whhg = s_wihg + 24*512;
  unsigned short* s_wihn = s_whhg + 24*512;
  unsigned short* s_whhn = s_wihn + 24*512;
  unsigned short* s_we1  = s_whhn + 24*512;              // [8][1024]
  unsigned short* s_wq   = s_we1  + 8*1024;              // [8][1024]
  float* s_x    = (float*)(s_wq + 8*1024);               // staged vec 0
  float* s_y    = s_x + 512;                             // staged vec 1
  float* s_z    = s_y + 512;                             // staged vec 2
  float* s_gi0  = s_z + 512;                             // [24]
  float* s_bihg = s_gi0 + 24;
  float* s_bhhg = s_bihg + 24;
  float* s_bihn = s_bhhg + 24;
  float* s_bhhn = s_bihn + 24;
  float* s_be1  = s_bhhn + 24;                           // [8]
  float* s_bq   = s_be1 + 8;                             // [8]
  float* s_we2  = s_bq + 8;                              // [16] = [ld][j]
  float* s_be2  = s_we2 + 16;                            // [2]
  float* s_red  = s_be2 + 2;                             // [16]
  float* s_nll  = s_red + 16;                            // [1]

  const int b = blockIdx.x, tid = threadIdx.x;
  const int wv = tid >> 6, lane = tid & 63;

  int*   flags  = (int*)ws;                              // [64]
  int*   go     = (int*)(ws + 256);
  float* g_buf  = (float*)(ws + 512);                    // [2][512]
  float* h0     = (float*)(ws + 4608);                   // [512]
  float* qv     = (float*)(ws + 6656);                   // [512]
  float* ncur   = (float*)(ws + 8704);                   // [512]
  float* epart  = (float*)(ws + 10752);                  // [2][64]
  float* logits = (float*)(ws + 11264);                  // [128]
  float* ne     = (float*)(ws + 12288);                  // [128][512]
  float* Kc     = ne + NMAX*HD;                          // [128][512]

  // ---------------- S0: biases, bf16 weight slices, h0, g init ----------------
  if (tid < 24){
    int ld = tid / 3, gt = tid % 3;
    int row = gt * 512 + b * 8 + ld;
    s_bihg[tid] = bih_g[row]; s_bhhg[tid] = bhh_g[row];
    s_bihn[tid] = bih_n[row]; s_bhhn[tid] = bhh_n[row];
  }
  if (tid < 8){ s_be1[tid] = b_e1[b*8+tid]; s_bq[tid] = b_q[b*8+tid]; }
  if (tid < 16){ int ld = tid >> 1, j = tid & 1; s_we2[ld*2+j] = w_e2[j*512 + b*8 + ld]; }
  if (tid < 2) s_be2[tid] = b_e2[tid];
  if (tid == 0) s_nll[0] = 0.f;

  for (int r = wv; r < 24; r += 8){               // GRU slices: rows d,512+d,1024+d
    int ld = r / 3, gt = r % 3;
    long grow = (long)(gt*512 + b*8 + ld) * 512;
    #pragma unroll
    for (int k = 0; k < 8; ++k){
      int j = lane + (k << 6);
      s_wihg[r*512 + j] = f2bf(wih_g[grow + j]);
      s_whhg[r*512 + j] = f2bf(whh_g[grow + j]);
      s_wihn[r*512 + j] = f2bf(wih_n[grow + j]);
      s_whhn[r*512 + j] = f2bf(whh_n[grow + j]);
    }
  }
  {                                              // w_e1 / w_q rows (width 1024)
    long grow = (long)(b*8 + wv) * 1024;
    #pragma unroll
    for (int k = 0; k < 16; ++k){
      int j = lane + (k << 6);
      s_we1[wv*1024 + j] = f2bf(w_e1[grow + j]);
      s_wq [wv*1024 + j] = f2bf(w_q [grow + j]);
    }
  }
  s_x[tid] = node_init[tid];
  __syncthreads();
  {                                              // h0 slice (fp32 exact, one-shot)
    int d = b*8 + wv;
    float acc = dot512g(w_nip + (long)d*512, s_x, lane);
    if (lane == 0) h0[d] = acc + b_nip[d];
  }
  if (b == 0) g_buf[tid] = graph0[tid];
  int barcnt = 0;
  gbar(flags, go, ++barcnt);

  // ---------------- S1: gi0 = wih_g@h0 + bih_g (block-local) ----------------
  s_x[tid] = h0[tid];
  __syncthreads();
  for (int r = wv; r < 24; r += 8){
    float acc = dot512(s_wihg + r*512, s_x, lane);
    if (lane == 0) s_gi0[r] = acc + s_bihg[r];
  }
  __syncthreads();

  // ---------------- main sequential scan ----------------
  int cur = -1, gcur = 0;
  int pend = 0, pcur = 0, parg = 0;

  for (int t = 0; t < LSEQ; ++t){
    int a = actions[t];
    if (a < 0 || a >= 4) continue;               // STOP_NODE / pad: noop
    int arg = argseq[t];

    if (a == 0){ // -------- ADD_NODE: 1 barrier --------
      s_x[tid] = g_buf[gcur*512 + tid];
      if (cur >= 0) s_y[tid] = ne[(long)cur*512 + tid];
      __syncthreads();
      if (b == 0 && wv == 7) run_pend(pend, pcur, parg, epart, logits, s_be2, s_nll, lane);
      pend = 0;
      {
        int ld = wv, d = b*8 + ld;
        float ghr = dot512(s_whhg + (ld*3+0)*512, s_x, lane) + s_bhhg[ld*3+0];
        float ghz = dot512(s_whhg + (ld*3+1)*512, s_x, lane) + s_bhhg[ld*3+1];
        float ghn = dot512(s_whhg + (ld*3+2)*512, s_x, lane) + s_bhhg[ld*3+2];
        if (lane == 0){
          float r_ = sigm(s_gi0[ld*3+0] + ghr);
          float z_ = sigm(s_gi0[ld*3+1] + ghz);
          float n_ = tanhf(s_gi0[ld*3+2] + r_*ghn);
          g_buf[(gcur^1)*512 + d] = (1.f - z_)*n_ + z_*s_x[d];
          ne[(long)(cur+1)*512 + d] = h0[d];
        }
        if (cur >= 0){                           // freeze K_cache[cur]
          float kv = dot512g(w_k + (long)d*512, s_y, lane);
          if (lane == 0) Kc[(long)cur*512 + d] = kv;
        }
      }
      gbar(flags, go, ++barcnt);
      gcur ^= 1; cur += 1;
    }
    else if (a == 1 || a == 3){ // -------- ADD_EDGE / STOP_EDGE: 1 barrier --------
      s_x[tid] = g_buf[gcur*512 + tid];
      s_y[tid] = ne[(long)cur*512 + tid];
      __syncthreads();
      if (b == 0 && wv == 7) run_pend(pend, pcur, parg, epart, logits, s_be2, s_nll, lane);
      {
        int ld = wv;
        float hv = dot1024(s_we1 + ld*1024, s_x, s_y, lane) + s_be1[ld];
        hv = fmaxf(hv, 0.f);
        if (lane == 0){ s_red[ld*2+0] = hv * s_we2[ld*2+0]; s_red[ld*2+1] = hv * s_we2[ld*2+1]; }
      }
      __syncthreads();
      if (tid == 0){
        float p0 = 0.f, p1 = 0.f;
        #pragma unroll
        for (int i = 0; i < 8; ++i){ p0 += s_red[i*2]; p1 += s_red[i*2+1]; }
        epart[b] = p0; epart[64 + b] = p1;
      }
      gbar(flags, go, ++barcnt);
      pend = (a == 1) ? 1 : 2;
    }
    else { // -------- CHOOSE_DEST: 2 barriers --------
      // phase A: q = w_q@[g;curv]+b_q ; new_cur = GRU_n(chosen, curv) -> tmp
      s_x[tid] = g_buf[gcur*512 + tid];
      s_y[tid] = ne[(long)cur*512 + tid];
      s_z[tid] = ne[(long)arg*512 + tid];
      __syncthreads();
      if (b == 0 && wv == 7) run_pend(pend, pcur, parg, epart, logits, s_be2, s_nll, lane);
      pend = 0;
      {
        int ld = wv, d = b*8 + ld;
        float qd = dot1024(s_wq + ld*1024, s_x, s_y, lane) + s_bq[ld];
        if (lane == 0) qv[d] = qd;
        float gir = dot512(s_wihn + (ld*3+0)*512, s_z, lane) + s_bihn[ld*3+0];
        float giz = dot512(s_wihn + (ld*3+1)*512, s_z, lane) + s_bihn[ld*3+1];
        float gin = dot512(s_wihn + (ld*3+2)*512, s_z, lane) + s_bihn[ld*3+2];
        float ghr = dot512(s_whhn + (ld*3+0)*512, s_y, lane) + s_bhhn[ld*3+0];
        float ghz = dot512(s_whhn + (ld*3+1)*512, s_y, lane) + s_bhhn[ld*3+1];
        float ghn = dot512(s_whhn + (ld*3+2)*512, s_y, lane) + s_bhhn[ld*3+2];
        if (lane == 0){
          float r_ = sigm(gir + ghr), z_ = sigm(giz + ghz);
          float n_ = tanhf(gin + r_*ghn);
          ncur[d] = (1.f - z_)*n_ + z_*s_y[d];
        }
      }
      gbar(flags, go, ++barcnt);
      // phase B: logits = Kc·q ; g2 = GRU_g(new_cur, g) ; commit ne[cur]
      s_x[tid] = qv[tid];
      s_y[tid] = ncur[tid];
      s_z[tid] = g_buf[gcur*512 + tid];
      __syncthreads();
      {
        int ld = wv, d = b*8 + ld;
        float gir = dot512(s_wihg + (ld*3+0)*512, s_y, lane) + s_bihg[ld*3+0];
        float giz = dot512(s_wihg + (ld*3+1)*512, s_y, lane) + s_bihg[ld*3+1];
        float gin = dot512(s_wihg + (ld*3+2)*512, s_y, lane) + s_bihg[ld*3+2];
        float ghr = dot512(s_whhg + (ld*3+0)*512, s_z, lane) + s_bhhg[ld*3+0];
        float ghz = dot512(s_whhg + (ld*3+1)*512, s_z, lane) + s_bhhg[ld*3+1];
        float ghn = dot512(s_whhg + (ld*3+2)*512, s_z, lane) + s_bhhg[ld*3+2];
        if (lane == 0){
          float r_ = sigm(gir + ghr), z_ = sigm(giz + ghz);
          float n_ = tanhf(gin + r_*ghn);
          g_buf[(gcur^1)*512 + d] = (1.f - z_)*n_ + z_*s_z[d];
          ne[(long)cur*512 + d] = s_y[d];
        }
        if (wv < 2){                             // destination logits
          int i = b + wv*64;
          if (i < cur){
            float lv = dot512g(Kc + (long)i*512, s_x, lane);
            if (lane == 0) logits[i] = lv;
          }
        }
      }
      gbar(flags, go, ++barcnt);
      gcur ^= 1;
      pend = 3; pcur = cur; parg = arg;
    }
  }

  // drain final pending log-softmax and emit nll
  if (b == 0 && wv == 7){
    run_pend(pend, pcur, parg, epart, logits, s_be2, s_nll, lane);
    if (lane == 0) out[0] = s_nll[0];
  }
}

extern "C" void kernel_launch(void* const* d_in, const int* in_sizes, int n_in,
                              void* d_out, int out_size, void* d_ws, size_t ws_size,
                              hipStream_t stream) {
  (void)in_sizes; (void)n_in; (void)out_size; (void)ws_size;
  // zero barrier flags + go (graph replays do not re-poison d_ws)
  hipMemsetAsync(d_ws, 0, 512, stream);
  hipFuncSetAttribute((const void*)dgmg_kernel,
                      hipFuncAttributeMaxDynamicSharedMemorySize, SMEM_BYTES);
  dgmg_kernel<<<NBLK, NTHR, SMEM_BYTES, stream>>>(
      (const int*)d_in[0], (const int*)d_in[1],
      (const float*)d_in[2], (const float*)d_in[3], (const float*)d_in[4],
      (const float*)d_in[5], (const float*)d_in[6],
      (const float*)d_in[7], (const float*)d_in[8],
      (const float*)d_in[9], (const float*)d_in[10],
      (const float*)d_in[11],                      /* w_k ; b_k unused (cancels) */
      (const float*)d_in[13], (const float*)d_in[14],
      (const float*)d_in[15], (const float*)d_in[16],
      (const float*)d_in[17], (const float*)d_in[18],
      (const float*)d_in[19], (const float*)d_in[20],
      (const float*)d_in[21],
      (float*)d_out, (unsigned char*)d_ws);
}

// Round 2
// 5196.474 us; speedup vs baseline: 3.9654x; 3.9654x over previous
//
#include <hip/hip_runtime.h>
#include <math.h>

#define NBLK 64
#define NTHR 512
#define HD   512
#define NMAX 128
#define LSEQ 1024

// ---------------- helpers ----------------
__device__ __forceinline__ float bf2f(unsigned short u){
  union { unsigned int i; float f; } v; v.i = ((unsigned int)u) << 16; return v.f;
}
__device__ __forceinline__ unsigned short f2bf(float f){
  union { float f; unsigned int i; } v; v.f = f;
  unsigned int x = v.i;
  return (unsigned short)((x + 0x7fffu + ((x >> 16) & 1u)) >> 16);
}
// coherent (agent-scope, cache-bypassing) load/store: no fences needed anywhere
__device__ __forceinline__ float gld(const float* p){
  return __hip_atomic_load(const_cast<float*>(p), __ATOMIC_RELAXED, __HIP_MEMORY_SCOPE_AGENT);
}
__device__ __forceinline__ void gst(float* p, float v){
  __hip_atomic_store(p, v, __ATOMIC_RELAXED, __HIP_MEMORY_SCOPE_AGENT);
}
__device__ __forceinline__ float wred(float a){
  #pragma unroll
  for (int off = 32; off; off >>= 1) a += __shfl_xor(a, off);
  return a;
}
__device__ __forceinline__ float wredmax(float a){
  #pragma unroll
  for (int off = 32; off; off >>= 1) a = fmaxf(a, __shfl_xor(a, off));
  return a;
}
// bf16 LDS row (len 512) dot fp32 LDS vector
__device__ __forceinline__ float dot512(const unsigned short* w, const float* x, int lane){
  float acc = 0.f;
  #pragma unroll
  for (int k = 0; k < 8; ++k){ int j = lane + (k << 6); acc += bf2f(w[j]) * x[j]; }
  return wred(acc);
}
// bf16 LDS row (len 1024) dot [x ; y]
__device__ __forceinline__ float dot1024(const unsigned short* w, const float* x, const float* y, int lane){
  float acc = 0.f;
  #pragma unroll
  for (int k = 0; k < 8; ++k){ int j = lane + (k << 6); acc += bf2f(w[j]) * x[j]; }
  #pragma unroll
  for (int k = 0; k < 8; ++k){ int j = lane + (k << 6); acc += bf2f(w[512 + j]) * y[j]; }
  return wred(acc);
}
// fp32 global (read-only input) row dot fp32 LDS vector
__device__ __forceinline__ float dot512g(const float* __restrict__ w, const float* x, int lane){
  float acc = 0.f;
  #pragma unroll
  for (int k = 0; k < 8; ++k){ int j = lane + (k << 6); acc += w[j] * x[j]; }
  return wred(acc);
}
// coherent ws row dot fp32 LDS vector
__device__ __forceinline__ float dot512a(const float* w, const float* x, int lane){
  float acc = 0.f;
  #pragma unroll
  for (int k = 0; k < 8; ++k){ int j = lane + (k << 6); acc += gld(w + j) * x[j]; }
  return wred(acc);
}
__device__ __forceinline__ float sigm(float x){ return 1.f / (1.f + __expf(-x)); }

// all-to-all single-hop grid barrier. All cross-block data moves via
// agent-scope coherent atomics, so the only ordering needed is vmcnt(0)
// (stores complete at the coherence point) -- NO cache maintenance.
__device__ __forceinline__ void gbar(int* flags, int target, int tid){
  asm volatile("s_waitcnt vmcnt(0)" ::: "memory");
  __syncthreads();                       // all waves' coherent stores retired
  if (tid == 0)
    __hip_atomic_store(&flags[blockIdx.x], target, __ATOMIC_RELAXED, __HIP_MEMORY_SCOPE_AGENT);
  if (tid < NBLK){
    while (__hip_atomic_load(&flags[tid], __ATOMIC_RELAXED, __HIP_MEMORY_SCOPE_AGENT) < target) {}
  }
  __syncthreads();
}

// pending scalar log-softmax work, executed by block 0, wave 7 only.
// pend: 0 none, 1 add_edge(idx 0), 2 stop_edge(idx 1), 3 choose_dest
__device__ __forceinline__ void run_pend(int pend, int pcur, int parg,
    const float* epart, const float* logits, const float* s_be2, float* s_nll, int lane){
  if (pend == 1 || pend == 2){
    float p0 = wred(gld(epart + lane));
    float p1 = wred(gld(epart + 64 + lane));
    if (lane == 0){
      float l0 = p0 + s_be2[0], l1 = p1 + s_be2[1];
      float m = fmaxf(l0, l1);
      float lse = m + logf(__expf(l0 - m) + __expf(l1 - m));
      s_nll[0] += lse - ((pend == 1) ? l0 : l1);
    }
  } else if (pend == 3){
    float x0 = (lane < pcur)      ? gld(logits + lane)      : -INFINITY;
    float x1 = (lane + 64 < pcur) ? gld(logits + lane + 64) : -INFINITY;
    float m = wredmax(fmaxf(x0, x1));
    float s = wred(__expf(x0 - m) + __expf(x1 - m));   // exp(-inf - m) == 0
    float la = (parg < 64) ? __shfl(x0, parg) : __shfl(x1, parg - 64);
    if (lane == 0) s_nll[0] += (m + logf(s)) - la;
  }
}

#define SMEM_BYTES (4*24*512*2 + 2*8*1024*2 + 4*(3*512 + 24*5 + 8 + 8 + 16 + 2 + 16 + 1))

__global__ void __launch_bounds__(NTHR, 1)
dgmg_kernel(const int* __restrict__ actions, const int* __restrict__ argseq,
            const float* __restrict__ node_init, const float* __restrict__ w_nip, const float* __restrict__ b_nip,
            const float* __restrict__ w_e1, const float* __restrict__ b_e1,
            const float* __restrict__ w_e2, const float* __restrict__ b_e2,
            const float* __restrict__ w_q, const float* __restrict__ b_q,
            const float* __restrict__ w_k,
            const float* __restrict__ wih_n, const float* __restrict__ whh_n,
            const float* __restrict__ bih_n, const float* __restrict__ bhh_n,
            const float* __restrict__ wih_g, const float* __restrict__ whh_g,
            const float* __restrict__ bih_g, const float* __restrict__ bhh_g,
            const float* __restrict__ graph0,
            float* __restrict__ out, unsigned char* __restrict__ ws)
{
  extern __shared__ unsigned char smem[];
  unsigned short* s_wihg = (unsigned short*)smem;        // [24][512]
  unsigned short* s_whhg = s_wihg + 24*512;
  unsigned short* s_wihn = s_whhg + 24*512;
  unsigned short* s_whhn = s_wihn + 24*512;
  unsigned short* s_we1  = s_whhn + 24*512;              // [8][1024]
  unsigned short* s_wq   = s_we1  + 8*1024;              // [8][1024]
  float* s_x    = (float*)(s_wq + 8*1024);               // staged vec 0
  float* s_y    = s_x + 512;                             // staged vec 1
  float* s_z    = s_y + 512;                             // staged vec 2
  float* s_gi0  = s_z + 512;                             // [24]
  float* s_bihg = s_gi0 + 24;
  float* s_bhhg = s_bihg + 24;
  float* s_bihn = s_bhhg + 24;
  float* s_bhhn = s_bihn + 24;
  float* s_be1  = s_bhhn + 24;                           // [8]
  float* s_bq   = s_be1 + 8;                             // [8]
  float* s_we2  = s_bq + 8;                              // [16] = [ld][j]
  float* s_be2  = s_we2 + 16;                            // [2]
  float* s_red  = s_be2 + 2;                             // [16]
  float* s_nll  = s_red + 16;                            // [1]

  const int b = blockIdx.x, tid = threadIdx.x;
  const int wv = tid >> 6, lane = tid & 63;

  int*   flags  = (int*)ws;                              // [64]
  float* g_buf  = (float*)(ws + 512);                    // [2][512]
  float* h0     = (float*)(ws + 4608);                   // [512]
  float* qv     = (float*)(ws + 6656);                   // [512]
  float* ncur   = (float*)(ws + 8704);                   // [512]
  float* epart  = (float*)(ws + 10752);                  // [2][64]
  float* logits = (float*)(ws + 11264);                  // [128]
  float* ne     = (float*)(ws + 12288);                  // [128][512]
  float* Kc     = ne + NMAX*HD;                          // [128][512]

  // ---------------- S0: biases, bf16 weight slices, h0, g init ----------------
  if (tid < 24){
    int ld = tid / 3, gt = tid % 3;
    int row = gt * 512 + b * 8 + ld;
    s_bihg[tid] = bih_g[row]; s_bhhg[tid] = bhh_g[row];
    s_bihn[tid] = bih_n[row]; s_bhhn[tid] = bhh_n[row];
  }
  if (tid < 8){ s_be1[tid] = b_e1[b*8+tid]; s_bq[tid] = b_q[b*8+tid]; }
  if (tid < 16){ int ld = tid >> 1, j = tid & 1; s_we2[ld*2+j] = w_e2[j*512 + b*8 + ld]; }
  if (tid < 2) s_be2[tid] = b_e2[tid];
  if (tid == 0) s_nll[0] = 0.f;

  for (int r = wv; r < 24; r += 8){               // GRU slices: rows d,512+d,1024+d
    int ld = r / 3, gt = r % 3;
    long grow = (long)(gt*512 + b*8 + ld) * 512;
    #pragma unroll
    for (int k = 0; k < 8; ++k){
      int j = lane + (k << 6);
      s_wihg[r*512 + j] = f2bf(wih_g[grow + j]);
      s_whhg[r*512 + j] = f2bf(whh_g[grow + j]);
      s_wihn[r*512 + j] = f2bf(wih_n[grow + j]);
      s_whhn[r*512 + j] = f2bf(whh_n[grow + j]);
    }
  }
  {                                              // w_e1 / w_q rows (width 1024)
    long grow = (long)(b*8 + wv) * 1024;
    #pragma unroll
    for (int k = 0; k < 16; ++k){
      int j = lane + (k << 6);
      s_we1[wv*1024 + j] = f2bf(w_e1[grow + j]);
      s_wq [wv*1024 + j] = f2bf(w_q [grow + j]);
    }
  }
  s_x[tid] = node_init[tid];
  __syncthreads();
  float h0d;                                     // this wave's h0[b*8+wv] (all lanes)
  {                                              // h0 slice (fp32 exact, one-shot)
    int d = b*8 + wv;
    float acc = dot512g(w_nip + (long)d*512, s_x, lane);
    h0d = acc + b_nip[d];
    if (lane == 0) gst(&h0[d], h0d);
  }
  if (b == 0) gst(&g_buf[tid], graph0[tid]);
  int barcnt = 0;
  gbar(flags, ++barcnt, tid);

  // ---------------- S1: gi0 = wih_g@h0 + bih_g (block-local) ----------------
  s_x[tid] = gld(&h0[tid]);
  __syncthreads();
  for (int r = wv; r < 24; r += 8){
    float acc = dot512(s_wihg + r*512, s_x, lane);
    if (lane == 0) s_gi0[r] = acc + s_bihg[r];
  }
  __syncthreads();

  // ---------------- main sequential scan ----------------
  int cur = -1, gcur = 0;
  int pend = 0, pcur = 0, parg = 0;

  for (int t = 0; t < LSEQ; ++t){
    int a = actions[t];
    if (a < 0 || a >= 4) continue;               // STOP_NODE / pad: noop
    int arg = argseq[t];

    if (a == 0){ // -------- ADD_NODE: 1 barrier --------
      s_x[tid] = gld(&g_buf[gcur*512 + tid]);
      if (cur >= 0) s_y[tid] = gld(&ne[(long)cur*512 + tid]);
      __syncthreads();
      if (b == 0 && wv == 7) run_pend(pend, pcur, parg, epart, logits, s_be2, s_nll, lane);
      pend = 0;
      {
        int ld = wv, d = b*8 + ld;
        float ghr = dot512(s_whhg + (ld*3+0)*512, s_x, lane) + s_bhhg[ld*3+0];
        float ghz = dot512(s_whhg + (ld*3+1)*512, s_x, lane) + s_bhhg[ld*3+1];
        float ghn = dot512(s_whhg + (ld*3+2)*512, s_x, lane) + s_bhhg[ld*3+2];
        if (lane == 0){
          float r_ = sigm(s_gi0[ld*3+0] + ghr);
          float z_ = sigm(s_gi0[ld*3+1] + ghz);
          float n_ = tanhf(s_gi0[ld*3+2] + r_*ghn);
          gst(&g_buf[(gcur^1)*512 + d], (1.f - z_)*n_ + z_*s_x[d]);
          gst(&ne[(long)(cur+1)*512 + d], h0d);
        }
        if (cur >= 0){                           // freeze K_cache[cur]
          float kv = dot512g(w_k + (long)d*512, s_y, lane);
          if (lane == 0) gst(&Kc[(long)cur*512 + d], kv);
        }
      }
      gbar(flags, ++barcnt, tid);
      gcur ^= 1; cur += 1;
    }
    else if (a == 1 || a == 3){ // -------- ADD_EDGE / STOP_EDGE: 1 barrier --------
      s_x[tid] = gld(&g_buf[gcur*512 + tid]);
      s_y[tid] = gld(&ne[(long)cur*512 + tid]);
      __syncthreads();
      if (b == 0 && wv == 7) run_pend(pend, pcur, parg, epart, logits, s_be2, s_nll, lane);
      {
        int ld = wv;
        float hv = dot1024(s_we1 + ld*1024, s_x, s_y, lane) + s_be1[ld];
        hv = fmaxf(hv, 0.f);
        if (lane == 0){ s_red[ld*2+0] = hv * s_we2[ld*2+0]; s_red[ld*2+1] = hv * s_we2[ld*2+1]; }
      }
      __syncthreads();
      if (tid == 0){
        float p0 = 0.f, p1 = 0.f;
        #pragma unroll
        for (int i = 0; i < 8; ++i){ p0 += s_red[i*2]; p1 += s_red[i*2+1]; }
        gst(&epart[b], p0); gst(&epart[64 + b], p1);
      }
      gbar(flags, ++barcnt, tid);
      pend = (a == 1) ? 1 : 2;
    }
    else { // -------- CHOOSE_DEST: 2 barriers --------
      // phase A: q = w_q@[g;curv]+b_q ; new_cur = GRU_n(chosen, curv) -> tmp
      s_x[tid] = gld(&g_buf[gcur*512 + tid]);
      s_y[tid] = gld(&ne[(long)cur*512 + tid]);
      s_z[tid] = gld(&ne[(long)arg*512 + tid]);
      __syncthreads();
      if (b == 0 && wv == 7) run_pend(pend, pcur, parg, epart, logits, s_be2, s_nll, lane);
      pend = 0;
      {
        int ld = wv, d = b*8 + ld;
        float qd = dot1024(s_wq + ld*1024, s_x, s_y, lane) + s_bq[ld];
        if (lane == 0) gst(&qv[d], qd);
        float gir = dot512(s_wihn + (ld*3+0)*512, s_z, lane) + s_bihn[ld*3+0];
        float giz = dot512(s_wihn + (ld*3+1)*512, s_z, lane) + s_bihn[ld*3+1];
        float gin = dot512(s_wihn + (ld*3+2)*512, s_z, lane) + s_bihn[ld*3+2];
        float ghr = dot512(s_whhn + (ld*3+0)*512, s_y, lane) + s_bhhn[ld*3+0];
        float ghz = dot512(s_whhn + (ld*3+1)*512, s_y, lane) + s_bhhn[ld*3+1];
        float ghn = dot512(s_whhn + (ld*3+2)*512, s_y, lane) + s_bhhn[ld*3+2];
        if (lane == 0){
          float r_ = sigm(gir + ghr), z_ = sigm(giz + ghz);
          float n_ = tanhf(gin + r_*ghn);
          gst(&ncur[d], (1.f - z_)*n_ + z_*s_y[d]);
        }
      }
      gbar(flags, ++barcnt, tid);
      // phase B: logits = Kc·q ; g2 = GRU_g(new_cur, g) ; commit ne[cur]
      s_x[tid] = gld(&qv[tid]);
      s_y[tid] = gld(&ncur[tid]);
      s_z[tid] = gld(&g_buf[gcur*512 + tid]);
      __syncthreads();
      {
        int ld = wv, d = b*8 + ld;
        float gir = dot512(s_wihg + (ld*3+0)*512, s_y, lane) + s_bihg[ld*3+0];
        float giz = dot512(s_wihg + (ld*3+1)*512, s_y, lane) + s_bihg[ld*3+1];
        float gin = dot512(s_wihg + (ld*3+2)*512, s_y, lane) + s_bihg[ld*3+2];
        float ghr = dot512(s_whhg + (ld*3+0)*512, s_z, lane) + s_bhhg[ld*3+0];
        float ghz = dot512(s_whhg + (ld*3+1)*512, s_z, lane) + s_bhhg[ld*3+1];
        float ghn = dot512(s_whhg + (ld*3+2)*512, s_z, lane) + s_bhhg[ld*3+2];
        if (lane == 0){
          float r_ = sigm(gir + ghr), z_ = sigm(giz + ghz);
          float n_ = tanhf(gin + r_*ghn);
          gst(&g_buf[(gcur^1)*512 + d], (1.f - z_)*n_ + z_*s_z[d]);
          gst(&ne[(long)cur*512 + d], s_y[d]);
        }
        if (wv < 2){                             // destination logits
          int i = b + wv*64;
          if (i < cur){
            float lv = dot512a(Kc + (long)i*512, s_x, lane);
            if (lane == 0) gst(&logits[i], lv);
          }
        }
      }
      gbar(flags, ++barcnt, tid);
      gcur ^= 1;
      pend = 3; pcur = cur; parg = arg;
    }
  }

  // drain final pending log-softmax and emit nll
  if (b == 0 && wv == 7){
    run_pend(pend, pcur, parg, epart, logits, s_be2, s_nll, lane);
    if (lane == 0) out[0] = s_nll[0];
  }
}

extern "C" void kernel_launch(void* const* d_in, const int* in_sizes, int n_in,
                              void* d_out, int out_size, void* d_ws, size_t ws_size,
                              hipStream_t stream) {
  (void)in_sizes; (void)n_in; (void)out_size; (void)ws_size;
  // zero barrier flags (graph replays do not re-poison d_ws)
  hipMemsetAsync(d_ws, 0, 512, stream);
  hipFuncSetAttribute((const void*)dgmg_kernel,
                      hipFuncAttributeMaxDynamicSharedMemorySize, SMEM_BYTES);
  dgmg_kernel<<<NBLK, NTHR, SMEM_BYTES, stream>>>(
      (const int*)d_in[0], (const int*)d_in[1],
      (const float*)d_in[2], (const float*)d_in[3], (const float*)d_in[4],
      (const float*)d_in[5], (const float*)d_in[6],
      (const float*)d_in[7], (const float*)d_in[8],
      (const float*)d_in[9], (const float*)d_in[10],
      (const float*)d_in[11],                      /* w_k ; b_k unused (cancels) */
      (const float*)d_in[13], (const float*)d_in[14],
      (const float*)d_in[15], (const float*)d_in[16],
      (const float*)d_in[17], (const float*)d_in[18],
      (const float*)d_in[19], (const float*)d_in[20],
      (const float*)d_in[21],
      (float*)d_out, (unsigned char*)d_ws);
}

// Round 3
// 3159.255 us; speedup vs baseline: 6.5224x; 1.6448x over previous
//
#include <hip/hip_runtime.h>
#include <math.h>

#define NBLK 64
#define NTHR 576        // 9 waves: 8 compute + 1 pend/reduction wave
#define LSEQ 1024

typedef unsigned int u32;
typedef unsigned short u16;

// ---------------- scalar helpers ----------------
__device__ __forceinline__ float bf2f(u16 u){ union{u32 i;float f;}v; v.i=(u32)u<<16; return v.f; }
__device__ __forceinline__ u16 f2bf(float f){ union{float f;u32 i;}v; v.f=f; u32 x=v.i;
  return (u16)((x + 0x7fffu + ((x>>16)&1u)) >> 16); }
__device__ __forceinline__ float sigm(float x){ return 1.f/(1.f+__expf(-x)); }

// coherent (agent-scope, cache-bypassing) accessors — no fences needed anywhere
__device__ __forceinline__ float gld(const float* p){ return __hip_atomic_load(const_cast<float*>(p), __ATOMIC_RELAXED, __HIP_MEMORY_SCOPE_AGENT); }
__device__ __forceinline__ void  gst(float* p, float v){ __hip_atomic_store(p, v, __ATOMIC_RELAXED, __HIP_MEMORY_SCOPE_AGENT); }
__device__ __forceinline__ u32   gldu(const u32* p){ return __hip_atomic_load(const_cast<u32*>(p), __ATOMIC_RELAXED, __HIP_MEMORY_SCOPE_AGENT); }
__device__ __forceinline__ void  gstu(u32* p, u32 v){ __hip_atomic_store(p, v, __ATOMIC_RELAXED, __HIP_MEMORY_SCOPE_AGENT); }
__device__ __forceinline__ int   gldi(const int* p){ return __hip_atomic_load(const_cast<int*>(p), __ATOMIC_RELAXED, __HIP_MEMORY_SCOPE_AGENT); }
__device__ __forceinline__ void  gsti(int* p, int v){ __hip_atomic_store(p, v, __ATOMIC_RELAXED, __HIP_MEMORY_SCOPE_AGENT); }

__device__ __forceinline__ void waitflag(const int* f, int target){
  int n = 0;
  while (gldi(f) < target){ if (++n > (1<<20)) break; }   // bail prevents hang on bug
}

// ---------------- wave reductions ----------------
__device__ __forceinline__ float wred(float a){
  #pragma unroll
  for (int off = 32; off; off >>= 1) a += __shfl_xor(a, off);
  return a;
}
__device__ __forceinline__ float wredmax(float a){
  #pragma unroll
  for (int off = 32; off; off >>= 1) a = fmaxf(a, __shfl_xor(a, off));
  return a;
}

// ---------------- dot products (wave-collective, 64 lanes) ----------------
// bf16 LDS row (512) . fp32 LDS vec
__device__ __forceinline__ float dot512(const u16* w, const float* x, int lane){
  float acc = 0.f;
  #pragma unroll
  for (int k = 0; k < 8; ++k){ int j = lane + (k<<6); acc += bf2f(w[j]) * x[j]; }
  return wred(acc);
}
// bf16 LDS row (1024) . [x ; y]
__device__ __forceinline__ float dot1024(const u16* w, const float* x, const float* y, int lane){
  float acc = 0.f;
  #pragma unroll
  for (int k = 0; k < 8; ++k){ int j = lane + (k<<6); acc += bf2f(w[j]) * x[j]; }
  #pragma unroll
  for (int k = 0; k < 8; ++k){ int j = lane + (k<<6); acc += bf2f(w[512+j]) * y[j]; }
  return wred(acc);
}
// fp32 global (read-only input) row . fp32 LDS vec
__device__ __forceinline__ float dot512g(const float* __restrict__ w, const float* x, int lane){
  float acc = 0.f;
  #pragma unroll
  for (int k = 0; k < 8; ++k){ int j = lane + (k<<6); acc += w[j] * x[j]; }
  return wred(acc);
}
// packed-bf16 coherent global row (256 dwords) . fp32 LDS vec
__device__ __forceinline__ float dot512h(const u32* row, const float* x, int lane){
  float acc = 0.f;
  #pragma unroll
  for (int k = 0; k < 4; ++k){
    u32 u = gldu(row + lane + (k<<6));
    int e = 2*(lane + (k<<6));
    acc += bf2f((u16)u) * x[e] + bf2f((u16)(u>>16)) * x[e+1];
  }
  return wred(acc);
}

// pending log-softmax reduction (runs on wave 8 of block 0)
// pend: 1 add_edge(sel 0), 2 stop_edge(sel 1), 3 choose_dest
__device__ __forceinline__ float pend_nll(int pend, int pcur, int parg, const float* Xe,
                                          int par1, float be2_0, float be2_1, int lane){
  if (pend == 1 || pend == 2){
    float p0 = 0.f, p1 = 0.f;
    #pragma unroll
    for (int w = 0; w < 8; ++w){
      p0 += gld(&Xe[(par1*64 + lane)*16 + w*2 + 0]);
      p1 += gld(&Xe[(par1*64 + lane)*16 + w*2 + 1]);
    }
    p0 = wred(p0); p1 = wred(p1);
    float l0 = p0 + be2_0, l1 = p1 + be2_1;
    float m = fmaxf(l0, l1);
    float lse = m + logf(__expf(l0-m) + __expf(l1-m));
    return lse - (pend == 1 ? l0 : l1);
  }
  if (pend == 3){
    float x0 = (lane < pcur)      ? gld(&Xe[(par1*64 + lane)*16 + 0]) : -__builtin_inff();
    float x1 = (lane + 64 < pcur) ? gld(&Xe[(par1*64 + lane)*16 + 2]) : -__builtin_inff();
    float m = wredmax(fmaxf(x0, x1));
    float s = wred(__expf(x0-m) + __expf(x1-m));
    float la = (parg < 64) ? __shfl(x0, parg) : __shfl(x1, parg - 64);
    return (m + logf(s)) - la;
  }
  return 0.f;
}

#define SMEM_BYTES (2*(4*24*512 + 2*8*1024) + 4*(6*512 + 4*24 + 3*8))

__global__ void __launch_bounds__(NTHR, 1)
dgmg_kernel(const int* __restrict__ actions, const int* __restrict__ argseq,
            const float* __restrict__ node_init, const float* __restrict__ w_nip, const float* __restrict__ b_nip,
            const float* __restrict__ w_e1, const float* __restrict__ b_e1,
            const float* __restrict__ w_e2, const float* __restrict__ b_e2,
            const float* __restrict__ w_q, const float* __restrict__ b_q,
            const float* __restrict__ w_k,
            const float* __restrict__ wih_n, const float* __restrict__ whh_n,
            const float* __restrict__ bih_n, const float* __restrict__ bhh_n,
            const float* __restrict__ wih_g, const float* __restrict__ whh_g,
            const float* __restrict__ bih_g, const float* __restrict__ bhh_g,
            const float* __restrict__ graph0,
            float* __restrict__ out, unsigned char* __restrict__ ws)
{
  extern __shared__ unsigned char smem[];
  u16* s_wihg = (u16*)smem;                 // [24][512]
  u16* s_whhg = s_wihg + 24*512;
  u16* s_wihn = s_whhg + 24*512;
  u16* s_whhn = s_wihn + 24*512;
  u16* s_we1  = s_whhn + 24*512;            // [8][1024]
  u16* s_wq   = s_we1 + 8*1024;             // [8][1024]
  float* s_g    = (float*)(s_wq + 8*1024);  // current graph vector
  float* s_curv = s_g + 512;                // current node vector (live)
  float* s_h0   = s_curv + 512;             // fresh-node embedding (static)
  float* s_nev  = s_h0 + 512;               // staged ne[arg]
  float* s_q    = s_nev + 512;              // staged q
  float* s_ncur = s_q + 512;                // staged new_cur
  float* s_bihg = s_ncur + 512;             // [24]
  float* s_bhhg = s_bihg + 24;
  float* s_bihn = s_bhhg + 24;
  float* s_bhhn = s_bihn + 24;
  float* s_be1  = s_bhhn + 24;              // [8]
  float* s_bq   = s_be1 + 8;                // [8]
  float* s_kc   = s_bq + 8;                 // [8] freeze gather

  const int b = blockIdx.x, tid = threadIdx.x;
  const int wv = tid >> 6, lane = tid & 63;
  const int d = b*8 + (wv < 8 ? wv : 0);

  // workspace layout
  int*   F   = (int*)ws;                    // [2][64] phase flags
  float* Xa  = (float*)(ws + 512);          // [2][512] exchange vec 0
  float* Xb  = (float*)(ws + 4608);         // [2][512] exchange vec 1
  float* Xe  = (float*)(ws + 8704);         // [2][64][8][2] extras
  u32*   neP = (u32*)(ws + 16896);          // [127][256] frozen nodes, packed bf16
  u32*   KcP = (u32*)(ws + 146944);         // [127][256] frozen keys,  packed bf16

  // ---------------- init: biases + bf16 weight slices ----------------
  if (tid < 24){
    int ld = tid/3, gt = tid%3;
    int row = gt*512 + b*8 + ld;
    s_bihg[tid] = bih_g[row]; s_bhhg[tid] = bhh_g[row];
    s_bihn[tid] = bih_n[row]; s_bhhn[tid] = bhh_n[row];
  }
  if (tid < 8){ s_be1[tid] = b_e1[b*8+tid]; s_bq[tid] = b_q[b*8+tid]; }

  for (int r = wv; r < 24; r += 8){         // waves 0-7 only (wv=8 starts past 24)
    int ld = r/3, gt = r%3;
    long grow = (long)(gt*512 + b*8 + ld) * 512;
    #pragma unroll
    for (int k = 0; k < 8; ++k){
      int j = lane + (k<<6);
      s_wihg[r*512+j] = f2bf(wih_g[grow+j]);
      s_whhg[r*512+j] = f2bf(whh_g[grow+j]);
      s_wihn[r*512+j] = f2bf(wih_n[grow+j]);
      s_whhn[r*512+j] = f2bf(whh_n[grow+j]);
    }
  }
  if (wv < 8){
    long grow = (long)(b*8 + wv) * 1024;
    #pragma unroll
    for (int k = 0; k < 16; ++k){
      int j = lane + (k<<6);
      s_we1[wv*1024+j] = f2bf(w_e1[grow+j]);
      s_wq [wv*1024+j] = f2bf(w_q [grow+j]);
    }
  }
  float we2_0 = 0.f, we2_1 = 0.f;
  if (wv < 8){ we2_0 = w_e2[d]; we2_1 = w_e2[512+d]; }
  float be2_0 = b_e2[0], be2_1 = b_e2[1];
  float nll = 0.f;

  // ---------------- INIT phase (ph=1): publish h0 + g0 ----------------
  if (tid < 512) s_g[tid] = node_init[tid];   // scratch use
  __syncthreads();
  if (wv < 8){
    float h0d = dot512g(w_nip + (long)d*512, s_g, lane) + b_nip[d];
    if (lane == 0){ gst(&Xb[512 + d], h0d); gst(&Xa[512 + d], graph0[d]); }
  }
  __syncthreads();                            // drains stores (vmcnt 0 per wave)
  if (tid == 0) gsti(&F[64 + b], 1);
  int ph = 2;

  float gi0r = 0.f, gi0z = 0.f, gi0n = 0.f;   // cached wih_g@h0 slice
  int cur = -1;
  int pend = 0, pcur = 0, parg = 0;
  int have_se = 0;
  bool first_an = true;

  // ---------------- main sequential scan ----------------
  for (int t = 0; t < LSEQ; ++t){
    int a = actions[t];
    if (a == 1) continue;                     // ADD_EDGE: fused into CD-A
    if (a == 3){ have_se = 1; continue; }     // STOP_EDGE: fused into next AN / drain
    if (a < 0 || a >= 4) continue;            // STOP_NODE / pad
    int arg = argseq[t];

    if (a == 0){ // ======== ADD_NODE (1 phase; absorbs pending STOP_EDGE) ========
      int par1 = (ph-1)&1, par = ph&1;
      if (tid < 512){
        waitflag(&F[par1*64 + (tid>>3)], ph-1);
        s_g[tid] = gld(&Xa[par1*512 + tid]);
        if (first_an) s_h0[tid] = gld(&Xb[par1*512 + tid]);
      }
      __syncthreads();
      if (b == 0 && wv == 8) nll += pend_nll(pend, pcur, parg, Xe, par1, be2_0, be2_1, lane);
      if (wv < 8){
        if (first_an){
          gi0r = dot512(s_wihg + (wv*3+0)*512, s_h0, lane) + s_bihg[wv*3+0];
          gi0z = dot512(s_wihg + (wv*3+1)*512, s_h0, lane) + s_bihg[wv*3+1];
          gi0n = dot512(s_wihg + (wv*3+2)*512, s_h0, lane) + s_bihg[wv*3+2];
        }
        if (have_se){                         // deferred STOP_EDGE e-logit partials
          float hv = fmaxf(dot1024(s_we1 + wv*1024, s_g, s_curv, lane) + s_be1[wv], 0.f);
          if (lane == 0){
            gst(&Xe[(par*64+b)*16 + wv*2 + 0], hv*we2_0);
            gst(&Xe[(par*64+b)*16 + wv*2 + 1], hv*we2_1);
          }
        }
        float ghr = dot512(s_whhg + (wv*3+0)*512, s_g, lane) + s_bhhg[wv*3+0];
        float ghz = dot512(s_whhg + (wv*3+1)*512, s_g, lane) + s_bhhg[wv*3+1];
        float ghn = dot512(s_whhg + (wv*3+2)*512, s_g, lane) + s_bhhg[wv*3+2];
        if (lane == 0){
          float r_ = sigm(gi0r + ghr), z_ = sigm(gi0z + ghz);
          float n_ = tanhf(gi0n + r_*ghn);
          gst(&Xa[par*512 + d], (1.f - z_)*n_ + z_*s_g[d]);
        }
        if (cur >= 0){                        // freeze key slice
          float kv = dot512g(w_k + (long)d*512, s_curv, lane);
          if (lane == 0) s_kc[wv] = kv;
        }
      }
      if (cur >= 0 && tid < 4){               // freeze node row (consumed at +1: pre-flag)
        float a0 = s_curv[8*b + 2*tid], a1 = s_curv[8*b + 2*tid + 1];
        gstu(&neP[cur*256 + b*4 + tid], (u32)f2bf(a0) | ((u32)f2bf(a1) << 16));
      }
      __syncthreads();                        // drains all data stores
      if (tid == 0) gsti(&F[par*64 + b], ph);
      if (cur >= 0 && tid < 4){               // key row (consumed at +2: post-flag OK)
        float a0 = s_kc[2*tid], a1 = s_kc[2*tid + 1];
        gstu(&KcP[cur*256 + b*4 + tid], (u32)f2bf(a0) | ((u32)f2bf(a1) << 16));
      }
      if (tid < 512) s_curv[tid] = s_h0[tid]; // new node vector
      pend = have_se ? 2 : 0;
      have_se = 0; first_an = false;
      cur += 1; ph += 1;
    }
    else { // ======== CHOOSE_DEST: 2 phases (phase A absorbs ADD_EDGE) ========
      // ---- CD-A: q + GRU_n + ADD_EDGE partials ----
      int par1 = (ph-1)&1, par = ph&1;
      if (tid < 512){
        waitflag(&F[par1*64 + (tid>>3)], ph-1);
        s_g[tid] = gld(&Xa[par1*512 + tid]);
      }
      if (tid < 256){
        u32 u = gldu(&neP[arg*256 + tid]);    // frozen row: flag-causality, no poll
        s_nev[2*tid]   = bf2f((u16)u);
        s_nev[2*tid+1] = bf2f((u16)(u >> 16));
      }
      __syncthreads();
      if (b == 0 && wv == 8) nll += pend_nll(pend, pcur, parg, Xe, par1, be2_0, be2_1, lane);
      if (wv < 8){
        float qd = dot1024(s_wq + wv*1024, s_g, s_curv, lane) + s_bq[wv];
        float hv = fmaxf(dot1024(s_we1 + wv*1024, s_g, s_curv, lane) + s_be1[wv], 0.f);
        float gir = dot512(s_wihn + (wv*3+0)*512, s_nev, lane) + s_bihn[wv*3+0];
        float giz = dot512(s_wihn + (wv*3+1)*512, s_nev, lane) + s_bihn[wv*3+1];
        float gin = dot512(s_wihn + (wv*3+2)*512, s_nev, lane) + s_bihn[wv*3+2];
        float ghr = dot512(s_whhn + (wv*3+0)*512, s_curv, lane) + s_bhhn[wv*3+0];
        float ghz = dot512(s_whhn + (wv*3+1)*512, s_curv, lane) + s_bhhn[wv*3+1];
        float ghn = dot512(s_whhn + (wv*3+2)*512, s_curv, lane) + s_bhhn[wv*3+2];
        if (lane == 0){
          gst(&Xa[par*512 + d], qd);
          gst(&Xe[(par*64+b)*16 + wv*2 + 0], hv*we2_0);
          gst(&Xe[(par*64+b)*16 + wv*2 + 1], hv*we2_1);
          float r_ = sigm(gir + ghr), z_ = sigm(giz + ghz);
          float n_ = tanhf(gin + r_*ghn);
          gst(&Xb[par*512 + d], (1.f - z_)*n_ + z_*s_curv[d]);
        }
      }
      __syncthreads();
      if (tid == 0) gsti(&F[par*64 + b], ph);
      pend = 1;                               // ADD_EDGE nll pending
      ph += 1;

      // ---- CD-B: GRU_g + destination logits ----
      par1 = (ph-1)&1; par = ph&1;
      if (tid < 512){
        waitflag(&F[par1*64 + (tid>>3)], ph-1);
        s_q[tid]    = gld(&Xa[par1*512 + tid]);
        s_ncur[tid] = gld(&Xb[par1*512 + tid]);
      }
      __syncthreads();
      if (b == 0 && wv == 8) nll += pend_nll(pend, pcur, parg, Xe, par1, be2_0, be2_1, lane);
      if (wv < 8){
        float gir = dot512(s_wihg + (wv*3+0)*512, s_ncur, lane) + s_bihg[wv*3+0];
        float giz = dot512(s_wihg + (wv*3+1)*512, s_ncur, lane) + s_bihg[wv*3+1];
        float gin = dot512(s_wihg + (wv*3+2)*512, s_ncur, lane) + s_bihg[wv*3+2];
        float ghr = dot512(s_whhg + (wv*3+0)*512, s_g, lane) + s_bhhg[wv*3+0];
        float ghz = dot512(s_whhg + (wv*3+1)*512, s_g, lane) + s_bhhg[wv*3+1];
        float ghn = dot512(s_whhg + (wv*3+2)*512, s_g, lane) + s_bhhg[wv*3+2];
        if (lane == 0){
          float r_ = sigm(gir + ghr), z_ = sigm(giz + ghz);
          float n_ = tanhf(gin + r_*ghn);
          gst(&Xa[par*512 + d], (1.f - z_)*n_ + z_*s_g[d]);
        }
        if (wv < 2){                          // destination logits (Kc_i . q)
          int i = b + wv*64;
          if (i < cur){
            float lv = dot512h(KcP + i*256, s_q, lane);
            if (lane == 0) gst(&Xe[(par*64+b)*16 + wv*2], lv);
          }
        }
      }
      __syncthreads();
      if (tid == 0) gsti(&F[par*64 + b], ph);
      if (tid < 512) s_curv[tid] = s_ncur[tid];
      pend = 3; pcur = cur; parg = arg;
      ph += 1;
    }
  }

  // ---------------- drain phase ----------------
  {
    int par1 = (ph-1)&1, par = ph&1;
    if (tid < 512){
      waitflag(&F[par1*64 + (tid>>3)], ph-1);
      s_g[tid] = gld(&Xa[par1*512 + tid]);
    }
    __syncthreads();
    if (b == 0 && wv == 8) nll += pend_nll(pend, pcur, parg, Xe, par1, be2_0, be2_1, lane);
    if (have_se && wv < 8){                   // final STOP_EDGE partials
      float hv = fmaxf(dot1024(s_we1 + wv*1024, s_g, s_curv, lane) + s_be1[wv], 0.f);
      if (lane == 0){
        gst(&Xe[(par*64+b)*16 + wv*2 + 0], hv*we2_0);
        gst(&Xe[(par*64+b)*16 + wv*2 + 1], hv*we2_1);
      }
    }
    __syncthreads();
    if (tid == 0) gsti(&F[par*64 + b], ph);
    if (b == 0 && wv == 8){
      waitflag(&F[par*64 + lane], ph);
      if (have_se) nll += pend_nll(2, 0, 0, Xe, par, be2_0, be2_1, lane);
      if (lane == 0) out[0] = nll;
    }
  }
}

extern "C" void kernel_launch(void* const* d_in, const int* in_sizes, int n_in,
                              void* d_out, int out_size, void* d_ws, size_t ws_size,
                              hipStream_t stream) {
  (void)in_sizes; (void)n_in; (void)out_size; (void)ws_size;
  // zero phase flags (graph replays do not re-poison d_ws)
  hipMemsetAsync(d_ws, 0, 512, stream);
  hipFuncSetAttribute((const void*)dgmg_kernel,
                      hipFuncAttributeMaxDynamicSharedMemorySize, SMEM_BYTES);
  dgmg_kernel<<<NBLK, NTHR, SMEM_BYTES, stream>>>(
      (const int*)d_in[0], (const int*)d_in[1],
      (const float*)d_in[2], (const float*)d_in[3], (const float*)d_in[4],
      (const float*)d_in[5], (const float*)d_in[6],
      (const float*)d_in[7], (const float*)d_in[8],
      (const float*)d_in[9], (const float*)d_in[10],
      (const float*)d_in[11],                      /* w_k ; b_k unused (cancels) */
      (const float*)d_in[13], (const float*)d_in[14],
      (const float*)d_in[15], (const float*)d_in[16],
      (const float*)d_in[17], (const float*)d_in[18],
      (const float*)d_in[19], (const float*)d_in[20],
      (const float*)d_in[21],
      (float*)d_out, (unsigned char*)d_ws);
}

// Round 4
// 2714.127 us; speedup vs baseline: 7.5921x; 1.1640x over previous
//
#include <hip/hip_runtime.h>
#include <math.h>

#define NBLK 64
#define NTHR 576        // 9 waves: 8 compute + 1 pend/reduction wave
#define LSEQ 1024

typedef unsigned int u32;
typedef unsigned short u16;
typedef unsigned long long u64;

// ---------------- scalar helpers ----------------
__device__ __forceinline__ float bf2f(u16 u){ union{u32 i;float f;}v; v.i=(u32)u<<16; return v.f; }
__device__ __forceinline__ u16 f2bf(float f){ union{float f;u32 i;}v; v.f=f; u32 x=v.i;
  return (u16)((x + 0x7fffu + ((x>>16)&1u)) >> 16); }
__device__ __forceinline__ float u2f(u32 u){ union{u32 i;float f;}v; v.i=u; return v.f; }
__device__ __forceinline__ u32  f2u(float f){ union{float f;u32 i;}v; v.f=f; return v.i; }
__device__ __forceinline__ float sigm(float x){ return 1.f/(1.f+__expf(-x)); }

// coherent (agent-scope) 8B atoms: (tag<<32)|payload — flag and data in ONE trip
__device__ __forceinline__ u64 gld64(const u64* p){ return __hip_atomic_load(const_cast<u64*>(p), __ATOMIC_RELAXED, __HIP_MEMORY_SCOPE_AGENT); }
__device__ __forceinline__ void gst64(u64* p, u64 v){ __hip_atomic_store(p, v, __ATOMIC_RELAXED, __HIP_MEMORY_SCOPE_AGENT); }
__device__ __forceinline__ u64 pollt(const u64* p, u32 tag){
  u64 v; int n = 0;
  do { v = gld64(p); } while ((u32)(v>>32) != tag && ++n < (1<<20));
  return v;
}

// ---------------- wave reductions ----------------
__device__ __forceinline__ float wred(float a){
  #pragma unroll
  for (int off = 32; off; off >>= 1) a += __shfl_xor(a, off);
  return a;
}
__device__ __forceinline__ float wredmax(float a){
  #pragma unroll
  for (int off = 32; off; off >>= 1) a = fmaxf(a, __shfl_xor(a, off));
  return a;
}

// ---------------- dot products (wave-collective, 64 lanes) ----------------
__device__ __forceinline__ float dot512(const u16* w, const float* x, int lane){
  float acc = 0.f;
  #pragma unroll
  for (int k = 0; k < 8; ++k){ int j = lane + (k<<6); acc += bf2f(w[j]) * x[j]; }
  return wred(acc);
}
__device__ __forceinline__ float dot1024(const u16* w, const float* x, const float* y, int lane){
  float acc = 0.f;
  #pragma unroll
  for (int k = 0; k < 8; ++k){ int j = lane + (k<<6); acc += bf2f(w[j]) * x[j]; }
  #pragma unroll
  for (int k = 0; k < 8; ++k){ int j = lane + (k<<6); acc += bf2f(w[512+j]) * y[j]; }
  return wred(acc);
}
__device__ __forceinline__ float dot512g(const float* __restrict__ w, const float* x, int lane){
  float acc = 0.f;
  #pragma unroll
  for (int k = 0; k < 8; ++k){ int j = lane + (k<<6); acc += w[j] * x[j]; }
  return wred(acc);
}

// LDS: bf16 weights (128KB) + fp32 state + local freeze caches
#define SMEM_BYTES (98304 + 32768 + 8192 + 4096 + 6144 + 544)

// wave-8 deferred log-softmax jobs (round-robin across blocks, off critical path)
#define RUN_JOBS() do { \
  if (wv == 8){ \
    if (dBV && b == dBo1){ \
      u64 v_ = pollt(XS + dBSlot*64 + lane, dBTag); \
      float x0 = sA0 + bf2f((u16)(v_ & 0xffff)); \
      float x1 = sA1 + bf2f((u16)((v_>>16) & 0xffff)); \
      x0 = (lane < dBcur) ? x0 : -__builtin_inff(); \
      x1 = (lane + 64 < dBcur) ? x1 : -__builtin_inff(); \
      float m_ = wredmax(fmaxf(x0, x1)); \
      float s_ = wred(__expf(x0 - m_) + __expf(x1 - m_)); \
      float la_ = (dBarg < 64) ? __shfl(x0, dBarg) : __shfl(x1, dBarg - 64); \
      if (lane == 0) nllw += (m_ + logf(s_)) - la_; \
    } \
    if (dAV && (b == dAo1 || b == dAo2)){ \
      const u64* P_ = XP + ((size_t)(dASlot*64 + lane))*64 + ((b == dAo2) ? 32 : 0); \
      float h0_ = 0.f, h1_ = 0.f; \
      for (int c_ = 0; c_ < 2; ++c_){ \
        u64 vv_[16]; int bad_; int nn_ = 0; \
        do { bad_ = 0; \
          _Pragma("unroll") for (int j_ = 0; j_ < 16; ++j_) vv_[j_] = gld64(P_ + c_*16 + j_); \
          _Pragma("unroll") for (int j_ = 0; j_ < 16; ++j_) bad_ |= ((u32)(vv_[j_]>>32) != dATag); \
        } while (bad_ && ++nn_ < (1<<20)); \
        _Pragma("unroll") for (int j_ = 0; j_ < 16; ++j_){ \
          h0_ += bf2f((u16)(vv_[j_] & 0xffff)); h1_ += bf2f((u16)((vv_[j_]>>16) & 0xffff)); } \
      } \
      if (b == dAo2) gst64(XS + dASlot*64 + lane, ((u64)dATag<<32) | (u32)f2bf(h0_) | ((u32)f2bf(h1_)<<16)); \
      else { sA0 = h0_; sA1 = h1_; } \
    } \
    if (aeV && b == aeOwn){ \
      u64 v_ = pollt(XE + aeSlot*64 + lane, aeTag); \
      float p0_ = wred(bf2f((u16)(v_ & 0xffff))); \
      float p1_ = wred(bf2f((u16)((v_>>16) & 0xffff))); \
      if (lane == 0){ \
        float l0_ = p0_ + be2_0, l1_ = p1_ + be2_1; \
        float m_ = fmaxf(l0_, l1_); \
        nllw += m_ + logf(__expf(l0_-m_) + __expf(l1_-m_)) - (aeSel ? l1_ : l0_); \
      } \
    } \
  } \
} while(0)

#define SHIFT_JOBS() do { \
  dBV = dAV; dBSlot = dASlot; dBo1 = dAo1; dBTag = dATag; dBcur = dAcur; dBarg = dAarg; \
  dAV = 0; aeV = 0; \
} while(0)

__global__ void __launch_bounds__(NTHR, 1)
dgmg_kernel(const int* __restrict__ actions, const int* __restrict__ argseq,
            const float* __restrict__ node_init, const float* __restrict__ w_nip, const float* __restrict__ b_nip,
            const float* __restrict__ w_e1, const float* __restrict__ b_e1,
            const float* __restrict__ w_e2, const float* __restrict__ b_e2,
            const float* __restrict__ w_q, const float* __restrict__ b_q,
            const float* __restrict__ w_k,
            const float* __restrict__ wih_n, const float* __restrict__ whh_n,
            const float* __restrict__ bih_n, const float* __restrict__ bhh_n,
            const float* __restrict__ wih_g, const float* __restrict__ whh_g,
            const float* __restrict__ bih_g, const float* __restrict__ bhh_g,
            const float* __restrict__ graph0,
            float* __restrict__ out, unsigned char* __restrict__ ws)
{
  extern __shared__ unsigned char smem[];
  u16* s_wihg = (u16*)smem;                 // [24][512]
  u16* s_whhg = s_wihg + 24*512;
  u16* s_wihn = s_whhg + 24*512;
  u16* s_whhn = s_wihn + 24*512;
  u16* s_we1  = s_whhn + 24*512;            // [8][1024]
  u16* s_wq   = s_we1 + 8*1024;             // [8][1024]
  float* s_g    = (float*)(s_wq + 8*1024);  // staged graph vector
  float* s_nc   = s_g + 512;                // staged ncur
  float* s_curv = s_nc + 512;               // current node vector (live)
  float* s_h0   = s_curv + 512;             // fresh-node embedding
  float* s_kloc = s_h0 + 512;               // [128][8] local k slices (freeze cache)
  float* s_bihg = s_kloc + 128*8;           // [24] x4
  float* s_bhhg = s_bihg + 24;
  float* s_bihn = s_bhhg + 24;
  float* s_bhhn = s_bihn + 24;
  float* s_be1  = s_bhhn + 24;              // [8]
  float* s_bq   = s_be1 + 8;                // [8]
  float* s_q8   = s_bq + 8;                 // [8] local q dims
  float* s_red  = s_q8 + 8;                 // [16] edge partial gather
  u16*   s_gin  = (u16*)(s_red + 16);       // [128][24] gi_n freeze cache (bf16)

  const int b = blockIdx.x, tid = threadIdx.x;
  const int wv = tid >> 6, lane = tid & 63;
  const int d = b*8 + ((wv < 8) ? wv : 0);

  // workspace: tagged u64 atoms
  u64* Xg = (u64*)ws;          // [2][512] g exchange
  u64* Xn = Xg + 1024;         // [2][512] ncur exchange
  u64* Xh = Xn + 1024;         // [512]    h0 broadcast
  u64* XE = Xh + 512;          // [4][64]  edge-logit partials (2xbf16)
  u64* XP = XE + 256;          // [2][64][64] dest-logit partials (2xbf16)
  u64* XS = XP + 8192;         // [2][64]  dest half-sums
  u64* XN = XS + 128;          // [64]     final nll pieces

  // ---------------- init: biases + bf16 weight slices ----------------
  if (tid < 24){
    int ld = tid/3, gt = tid%3;
    int row = gt*512 + b*8 + ld;
    s_bihg[tid] = bih_g[row]; s_bhhg[tid] = bhh_g[row];
    s_bihn[tid] = bih_n[row]; s_bhhn[tid] = bhh_n[row];
  }
  if (tid < 8){ s_be1[tid] = b_e1[b*8+tid]; s_bq[tid] = b_q[b*8+tid]; }

  for (int r = wv; r < 24; r += 8){         // waves 0-7 only
    int ld = r/3, gt = r%3;
    long grow = (long)(gt*512 + b*8 + ld) * 512;
    #pragma unroll
    for (int k = 0; k < 8; ++k){
      int j = lane + (k<<6);
      s_wihg[r*512+j] = f2bf(wih_g[grow+j]);
      s_whhg[r*512+j] = f2bf(whh_g[grow+j]);
      s_wihn[r*512+j] = f2bf(wih_n[grow+j]);
      s_whhn[r*512+j] = f2bf(whh_n[grow+j]);
    }
  }
  if (wv < 8){
    long grow = (long)(b*8 + wv) * 1024;
    #pragma unroll
    for (int k = 0; k < 16; ++k){
      int j = lane + (k<<6);
      s_we1[wv*1024+j] = f2bf(w_e1[grow+j]);
      s_wq [wv*1024+j] = f2bf(w_q [grow+j]);
    }
  }
  float we2_0 = w_e2[d], we2_1 = w_e2[512+d];
  float be2_0 = b_e2[0], be2_1 = b_e2[1];
  float nllw = 0.f;                          // wave-8 lane-0 nll accumulator
  float sA0 = 0.f, sA1 = 0.f;                // stage-A persistence (wave 8)

  // job state (uniform trace walk on every thread)
  int aeV=0, aeSlot=0, aeSel=0, aeOwn=0; u32 aeTag=0;
  int dAV=0, dASlot=0, dAo1=0, dAo2=0, dAcur=0, dAarg=0; u32 dATag=0;
  int dBV=0, dBSlot=0, dBo1=0, dBcur=0, dBarg=0; u32 dBTag=0;
  int ecnt=0, dcnt=0;

  // ---------------- INIT (ph=1): broadcast h0 ----------------
  if (tid < 512) s_g[tid] = node_init[tid];
  __syncthreads();
  if (wv < 8){
    float h0d = dot512g(w_nip + (long)d*512, s_g, lane) + b_nip[d];
    if (lane == 0) gst64(&Xh[d], (1ull<<32) | f2u(h0d));
  }
  __syncthreads();
  u32 ph = 2;

  float gi0r = 0.f, gi0z = 0.f, gi0n = 0.f;  // cached wih_g@h0 slice
  int cur = -1, have_se = 0;
  bool first_an = true;

  // ---------------- main sequential scan ----------------
  for (int t = 0; t < LSEQ; ++t){
    int a = actions[t];
    if (a == 1) continue;                    // ADD_EDGE fused into CD-A
    if (a == 3){ have_se = 1; continue; }    // STOP_EDGE fused into next AN / drain
    if (a < 0 || a >= 4) continue;

    if (a == 0){ // ======== ADD_NODE (1 phase; absorbs pending STOP_EDGE) ========
      int eslot = ecnt & 3;
      if (first_an){
        if (tid < 512){ u64 v = pollt(&Xh[tid], 1u); s_h0[tid] = u2f((u32)v); s_g[tid] = graph0[tid]; }
      } else {
        u32 gtag = ph-1; int gpar = gtag & 1;
        if (tid < 512){ u64 v = pollt(&Xg[gpar*512 + tid], gtag); s_g[tid] = u2f((u32)v); }
      }
      __syncthreads();
      RUN_JOBS();
      if (wv < 8){
        if (first_an){
          gi0r = dot512(s_wihg + (wv*3+0)*512, s_h0, lane) + s_bihg[wv*3+0];
          gi0z = dot512(s_wihg + (wv*3+1)*512, s_h0, lane) + s_bihg[wv*3+1];
          gi0n = dot512(s_wihg + (wv*3+2)*512, s_h0, lane) + s_bihg[wv*3+2];
        }
        float ghr = dot512(s_whhg + (wv*3+0)*512, s_g, lane) + s_bhhg[wv*3+0];
        float ghz = dot512(s_whhg + (wv*3+1)*512, s_g, lane) + s_bhhg[wv*3+1];
        float ghn = dot512(s_whhg + (wv*3+2)*512, s_g, lane) + s_bhhg[wv*3+2];
        if (lane == 0){
          float r_ = sigm(gi0r + ghr), z_ = sigm(gi0z + ghz);
          float n_ = tanhf(gi0n + r_*ghn);
          gst64(&Xg[(ph&1)*512 + d], ((u64)ph<<32) | f2u((1.f - z_)*n_ + z_*s_g[d]));  // FIRE
        }
        if (cur >= 0){                       // freeze caches (block-LOCAL, no exchange)
          float gr = dot512(s_wihn + (wv*3+0)*512, s_curv, lane) + s_bihn[wv*3+0];
          float gz = dot512(s_wihn + (wv*3+1)*512, s_curv, lane) + s_bihn[wv*3+1];
          float gn = dot512(s_wihn + (wv*3+2)*512, s_curv, lane) + s_bihn[wv*3+2];
          float kv = dot512g(w_k + (long)d*512, s_curv, lane);
          if (lane == 0){
            s_gin[cur*24 + wv*3+0] = f2bf(gr);
            s_gin[cur*24 + wv*3+1] = f2bf(gz);
            s_gin[cur*24 + wv*3+2] = f2bf(gn);
            s_kloc[cur*8 + wv] = kv;
          }
        }
        if (have_se){                        // deferred STOP_EDGE partials
          float hv = fmaxf(dot1024(s_we1 + wv*1024, s_g, s_curv, lane) + s_be1[wv], 0.f);
          if (lane == 0){ s_red[wv*2+0] = hv*we2_0; s_red[wv*2+1] = hv*we2_1; }
        }
      }
      __syncthreads();
      if (have_se && tid == 0){
        float p0 = 0.f, p1 = 0.f;
        #pragma unroll
        for (int i = 0; i < 8; ++i){ p0 += s_red[i*2]; p1 += s_red[i*2+1]; }
        gst64(&XE[eslot*64 + b], ((u64)ph<<32) | (u32)f2bf(p0) | ((u32)f2bf(p1)<<16));
      }
      if (tid < 512) s_curv[tid] = s_h0[tid];
      SHIFT_JOBS();
      if (have_se){ aeV=1; aeSlot=eslot; aeSel=1; aeOwn=ecnt&63; aeTag=ph; ecnt++; }
      have_se = 0; first_an = false;
      cur += 1; ph += 1;
    }
    else { // ======== CHOOSE_DEST: CD-A then CD-B ========
      int arg = argseq[t];
      // ---- CD-A: GRU_n (cache-fed) + q + AE partials + dest partials ----
      int eslot = ecnt & 3, dslot = dcnt & 1;
      {
        u32 gtag = ph-1; int gpar = gtag & 1;
        if (tid < 512){ u64 v = pollt(&Xg[gpar*512 + tid], gtag); s_g[tid] = u2f((u32)v); }
      }
      __syncthreads();
      RUN_JOBS();
      if (wv < 8){
        float ghr = dot512(s_whhn + (wv*3+0)*512, s_curv, lane) + s_bhhn[wv*3+0];
        float ghz = dot512(s_whhn + (wv*3+1)*512, s_curv, lane) + s_bhhn[wv*3+1];
        float ghn = dot512(s_whhn + (wv*3+2)*512, s_curv, lane) + s_bhhn[wv*3+2];
        float gr = bf2f(s_gin[arg*24 + wv*3+0]);
        float gz = bf2f(s_gin[arg*24 + wv*3+1]);
        float gn = bf2f(s_gin[arg*24 + wv*3+2]);
        if (lane == 0){
          float r_ = sigm(gr + ghr), z_ = sigm(gz + ghz);
          float n_ = tanhf(gn + r_*ghn);
          gst64(&Xn[(ph&1)*512 + d], ((u64)ph<<32) | f2u((1.f - z_)*n_ + z_*s_curv[d])); // FIRE ncur
        }
        float qd = dot1024(s_wq + wv*1024, s_g, s_curv, lane) + s_bq[wv];
        float hv = fmaxf(dot1024(s_we1 + wv*1024, s_g, s_curv, lane) + s_be1[wv], 0.f);
        if (lane == 0){ s_q8[wv] = qd; s_red[wv*2+0] = hv*we2_0; s_red[wv*2+1] = hv*we2_1; }
      }
      __syncthreads();
      if (tid < 64){                          // dest-logit partials (local k x local q)
        float pl0 = 0.f, pl1 = 0.f;
        #pragma unroll
        for (int k = 0; k < 8; ++k){
          pl0 += s_kloc[tid*8 + k]      * s_q8[k];
          pl1 += s_kloc[(tid+64)*8 + k] * s_q8[k];
        }
        gst64(&XP[((size_t)(dslot*64 + tid))*64 + b],
              ((u64)ph<<32) | (u32)f2bf(pl0) | ((u32)f2bf(pl1)<<16));
      }
      if (tid == 64){
        float p0 = 0.f, p1 = 0.f;
        #pragma unroll
        for (int i = 0; i < 8; ++i){ p0 += s_red[i*2]; p1 += s_red[i*2+1]; }
        gst64(&XE[eslot*64 + b], ((u64)ph<<32) | (u32)f2bf(p0) | ((u32)f2bf(p1)<<16));
      }
      SHIFT_JOBS();
      aeV=1; aeSlot=eslot; aeSel=0; aeOwn=ecnt&63; aeTag=ph; ecnt++;
      dAV=1; dASlot=dslot; dAo1=(2*dcnt)&63; dAo2=(2*dcnt+1)&63; dAcur=cur; dAarg=arg; dATag=ph;
      dcnt++;
      ph += 1;

      // ---- CD-B: GRU_g(ncur, g) ----
      {
        u32 ntag = ph-1; int npar = ntag & 1;
        if (tid < 512){ u64 v = pollt(&Xn[npar*512 + tid], ntag); s_nc[tid] = u2f((u32)v); }
      }
      __syncthreads();
      RUN_JOBS();
      if (wv < 8){
        float gir = dot512(s_wihg + (wv*3+0)*512, s_nc, lane) + s_bihg[wv*3+0];
        float giz = dot512(s_wihg + (wv*3+1)*512, s_nc, lane) + s_bihg[wv*3+1];
        float gin = dot512(s_wihg + (wv*3+2)*512, s_nc, lane) + s_bihg[wv*3+2];
        float ghr = dot512(s_whhg + (wv*3+0)*512, s_g, lane) + s_bhhg[wv*3+0];
        float ghz = dot512(s_whhg + (wv*3+1)*512, s_g, lane) + s_bhhg[wv*3+1];
        float ghn = dot512(s_whhg + (wv*3+2)*512, s_g, lane) + s_bhhg[wv*3+2];
        if (lane == 0){
          float r_ = sigm(gir + ghr), z_ = sigm(giz + ghz);
          float n_ = tanhf(gin + r_*ghn);
          gst64(&Xg[(ph&1)*512 + d], ((u64)ph<<32) | f2u((1.f - z_)*n_ + z_*s_g[d])); // FIRE g2
        }
      }
      __syncthreads();
      if (tid < 512) s_curv[tid] = s_nc[tid];
      SHIFT_JOBS();                           // stage-B of this CD due next phase
      ph += 1;
    }
  }

  // ---------------- drain: V1 (final SE partials + last stage-B), V2 (collect) ----------------
  {
    int eslot = ecnt & 3;
    u32 gtag = ph-1; int gpar = gtag & 1;
    if (tid < 512){ u64 v = pollt(&Xg[gpar*512 + tid], gtag); s_g[tid] = u2f((u32)v); }
    __syncthreads();
    RUN_JOBS();                               // last CD's stage-B
    if (have_se && wv < 8){
      float hv = fmaxf(dot1024(s_we1 + wv*1024, s_g, s_curv, lane) + s_be1[wv], 0.f);
      if (lane == 0){ s_red[wv*2+0] = hv*we2_0; s_red[wv*2+1] = hv*we2_1; }
    }
    __syncthreads();
    if (have_se && tid == 0){
      float p0 = 0.f, p1 = 0.f;
      #pragma unroll
      for (int i = 0; i < 8; ++i){ p0 += s_red[i*2]; p1 += s_red[i*2+1]; }
      gst64(&XE[eslot*64 + b], ((u64)ph<<32) | (u32)f2bf(p0) | ((u32)f2bf(p1)<<16));
    }
    // V2: block 0 finishes final SE pend, then global nll collect
    if (wv == 8){
      if (have_se && b == 0){
        u64 v = pollt(&XE[eslot*64 + lane], ph);
        float p0 = wred(bf2f((u16)(v & 0xffff)));
        float p1 = wred(bf2f((u16)((v>>16) & 0xffff)));
        if (lane == 0){
          float l0 = p0 + be2_0, l1 = p1 + be2_1;
          float m = fmaxf(l0, l1);
          nllw += m + logf(__expf(l0-m) + __expf(l1-m)) - l1;   // STOP_EDGE selects idx 1
        }
      }
      if (lane == 0) gst64(&XN[b], (0xFFFFull<<32) | f2u(nllw));
      if (b == 0){
        u64 v = pollt(&XN[lane], 0xFFFFu);
        float tot = wred(u2f((u32)v));
        if (lane == 0) out[0] = tot;
      }
    }
  }
}

extern "C" void kernel_launch(void* const* d_in, const int* in_sizes, int n_in,
                              void* d_out, int out_size, void* d_ws, size_t ws_size,
                              hipStream_t stream) {
  (void)in_sizes; (void)n_in; (void)out_size; (void)ws_size;
  // zero all tag-atom regions (11200 u64s) — exact-match tags then poison/replay-safe
  hipMemsetAsync(d_ws, 0, 89600, stream);
  hipFuncSetAttribute((const void*)dgmg_kernel,
                      hipFuncAttributeMaxDynamicSharedMemorySize, SMEM_BYTES);
  dgmg_kernel<<<NBLK, NTHR, SMEM_BYTES, stream>>>(
      (const int*)d_in[0], (const int*)d_in[1],
      (const float*)d_in[2], (const float*)d_in[3], (const float*)d_in[4],
      (const float*)d_in[5], (const float*)d_in[6],
      (const float*)d_in[7], (const float*)d_in[8],
      (const float*)d_in[9], (const float*)d_in[10],
      (const float*)d_in[11],                      /* w_k ; b_k unused (cancels) */
      (const float*)d_in[13], (const float*)d_in[14],
      (const float*)d_in[15], (const float*)d_in[16],
      (const float*)d_in[17], (const float*)d_in[18],
      (const float*)d_in[19], (const float*)d_in[20],
      (const float*)d_in[21],
      (float*)d_out, (unsigned char*)d_ws);
}

// Round 5
// 1101.519 us; speedup vs baseline: 18.7068x; 2.4640x over previous
//
#include <hip/hip_runtime.h>
#include <math.h>

#define NBLK 64
#define NTHR 576        // 9 waves: 8 compute + 1 job/reduction wave
#define LSEQ 1024

typedef unsigned int u32;
typedef unsigned short u16;
typedef unsigned long long u64;

// ---------------- scalar helpers ----------------
__device__ __forceinline__ float bf2f(u16 u){ union{u32 i;float f;}v; v.i=(u32)u<<16; return v.f; }
__device__ __forceinline__ u16 f2bf(float f){ union{float f;u32 i;}v; v.f=f; u32 x=v.i;
  return (u16)((x + 0x7fffu + ((x>>16)&1u)) >> 16); }
__device__ __forceinline__ float u2f(u32 u){ union{u32 i;float f;}v; v.i=u; return v.f; }
__device__ __forceinline__ u32  f2u(float f){ union{float f;u32 i;}v; v.f=f; return v.i; }
__device__ __forceinline__ float sigm(float x){ return 1.f/(1.f+__expf(-x)); }

// coherent (agent-scope) 8B atoms: (tag<<32)|payload
__device__ __forceinline__ u64 gld64(const u64* p){ return __hip_atomic_load(const_cast<u64*>(p), __ATOMIC_RELAXED, __HIP_MEMORY_SCOPE_AGENT); }
__device__ __forceinline__ void gst64(u64* p, u64 v){ __hip_atomic_store(p, v, __ATOMIC_RELAXED, __HIP_MEMORY_SCOPE_AGENT); }
__device__ __forceinline__ u64 pollt(const u64* p, u32 tag){
  u64 v; int n = 0;
  do { v = gld64(p); } while ((u32)(v>>32) != tag && ++n < (1<<20));
  return v;
}

// ---------------- reductions ----------------
// DPP-based full-wave(64) sum; result uniform (readlane 63). VALU-only, no DS ops.
__device__ __forceinline__ float wred(float a){
  a += __int_as_float(__builtin_amdgcn_update_dpp(0, __float_as_int(a), 0x111, 0xf, 0xf, true)); // row_shr:1
  a += __int_as_float(__builtin_amdgcn_update_dpp(0, __float_as_int(a), 0x112, 0xf, 0xf, true)); // row_shr:2
  a += __int_as_float(__builtin_amdgcn_update_dpp(0, __float_as_int(a), 0x114, 0xf, 0xf, true)); // row_shr:4
  a += __int_as_float(__builtin_amdgcn_update_dpp(0, __float_as_int(a), 0x118, 0xf, 0xf, true)); // row_shr:8
  a += __int_as_float(__builtin_amdgcn_update_dpp(0, __float_as_int(a), 0x142, 0xa, 0xf, true)); // row_bcast15, rows 1&3
  a += __int_as_float(__builtin_amdgcn_update_dpp(0, __float_as_int(a), 0x143, 0xc, 0xf, true)); // row_bcast31, rows 2&3
  return __int_as_float(__builtin_amdgcn_readlane(__float_as_int(a), 63));
}
// shfl versions for the (rare) job paths that need lane-indexed access
__device__ __forceinline__ float wredsh(float a){
  #pragma unroll
  for (int off = 32; off; off >>= 1) a += __shfl_xor(a, off);
  return a;
}
__device__ __forceinline__ float wredmaxsh(float a){
  #pragma unroll
  for (int off = 32; off; off >>= 1) a = fmaxf(a, __shfl_xor(a, off));
  return a;
}

// ---------------- packed dot helpers ----------------
// 4 u32 of packed bf16 (8 elems) x 8 fp32
__device__ __forceinline__ float dot8p(uint4 w, float4 a, float4 b2){
  float s;
  s  = u2f(w.x<<16)*a.x  + u2f(w.x&0xffff0000u)*a.y;
  s += u2f(w.y<<16)*a.z  + u2f(w.y&0xffff0000u)*a.w;
  s += u2f(w.z<<16)*b2.x + u2f(w.z&0xffff0000u)*b2.y;
  s += u2f(w.w<<16)*b2.z + u2f(w.w&0xffff0000u)*b2.w;
  return s;
}
__device__ __forceinline__ float dot4f(float4 w, float4 x){
  return w.x*x.x + w.y*x.y + w.z*x.z + w.w*x.w;
}
__device__ __forceinline__ uint4 pk8(float4 a, float4 b2){
  uint4 r;
  r.x = (u32)f2bf(a.x)  | ((u32)f2bf(a.y)<<16);
  r.y = (u32)f2bf(a.z)  | ((u32)f2bf(a.w)<<16);
  r.z = (u32)f2bf(b2.x) | ((u32)f2bf(b2.y)<<16);
  r.w = (u32)f2bf(b2.z) | ((u32)f2bf(b2.w)<<16);
  return r;
}

#define SMEM_BYTES 150048

// wave-8 deferred log-softmax jobs (round-robin across blocks, off critical path)
#define RUN_JOBS() do { \
  if (wv == 8){ \
    if (dBV && b == dBo1){ \
      u64 v_ = pollt(XS + dBSlot*64 + lane, dBTag); \
      float x0 = sA0 + bf2f((u16)(v_ & 0xffff)); \
      float x1 = sA1 + bf2f((u16)((v_>>16) & 0xffff)); \
      x0 = (lane < dBcur) ? x0 : -__builtin_inff(); \
      x1 = (lane + 64 < dBcur) ? x1 : -__builtin_inff(); \
      float m_ = wredmaxsh(fmaxf(x0, x1)); \
      float s_ = wredsh(__expf(x0 - m_) + __expf(x1 - m_)); \
      float la_ = (dBarg < 64) ? __shfl(x0, dBarg) : __shfl(x1, dBarg - 64); \
      if (lane == 0) nllw += (m_ + logf(s_)) - la_; \
    } \
    if (dAV && (b == dAo1 || b == dAo2)){ \
      const u64* P_ = XP + ((size_t)(dASlot*64 + lane))*64 + ((b == dAo2) ? 32 : 0); \
      float h0_ = 0.f, h1_ = 0.f; \
      for (int c_ = 0; c_ < 2; ++c_){ \
        u64 vv_[16]; int bad_; int nn_ = 0; \
        do { bad_ = 0; \
          _Pragma("unroll") for (int j_ = 0; j_ < 16; ++j_) vv_[j_] = gld64(P_ + c_*16 + j_); \
          _Pragma("unroll") for (int j_ = 0; j_ < 16; ++j_) bad_ |= ((u32)(vv_[j_]>>32) != dATag); \
        } while (bad_ && ++nn_ < (1<<20)); \
        _Pragma("unroll") for (int j_ = 0; j_ < 16; ++j_){ \
          h0_ += bf2f((u16)(vv_[j_] & 0xffff)); h1_ += bf2f((u16)((vv_[j_]>>16) & 0xffff)); } \
      } \
      if (b == dAo2) gst64(XS + dASlot*64 + lane, ((u64)dATag<<32) | (u32)f2bf(h0_) | ((u32)f2bf(h1_)<<16)); \
      else { sA0 = h0_; sA1 = h1_; } \
    } \
    if (aeV && b == aeOwn){ \
      u64 v_ = pollt(XE + aeSlot*64 + lane, aeTag); \
      float p0_ = wredsh(bf2f((u16)(v_ & 0xffff))); \
      float p1_ = wredsh(bf2f((u16)((v_>>16) & 0xffff))); \
      if (lane == 0){ \
        float l0_ = p0_ + be2_0, l1_ = p1_ + be2_1; \
        float m_ = fmaxf(l0_, l1_); \
        nllw += m_ + logf(__expf(l0_-m_) + __expf(l1_-m_)) - (aeSel ? l1_ : l0_); \
      } \
    } \
  } \
} while(0)

#define SHIFT_JOBS() do { \
  dBV = dAV; dBSlot = dASlot; dBo1 = dAo1; dBTag = dATag; dBcur = dAcur; dBarg = dAarg; \
  dAV = 0; aeV = 0; \
} while(0)

__global__ void __launch_bounds__(NTHR, 1)
dgmg_kernel(const int* __restrict__ actions, const int* __restrict__ argseq,
            const float* __restrict__ node_init, const float* __restrict__ w_nip, const float* __restrict__ b_nip,
            const float* __restrict__ w_e1, const float* __restrict__ b_e1,
            const float* __restrict__ w_e2, const float* __restrict__ b_e2,
            const float* __restrict__ w_q, const float* __restrict__ b_q,
            const float* __restrict__ w_k,
            const float* __restrict__ wih_n, const float* __restrict__ whh_n,
            const float* __restrict__ bih_n, const float* __restrict__ bhh_n,
            const float* __restrict__ wih_g, const float* __restrict__ whh_g,
            const float* __restrict__ bih_g, const float* __restrict__ bhh_g,
            const float* __restrict__ graph0,
            float* __restrict__ out, unsigned char* __restrict__ ws)
{
  extern __shared__ unsigned char smem[];
  u16* s_wihg = (u16*)smem;                 // [24][512] packed bf16
  u16* s_whhg = s_wihg + 24*512;
  u16* s_wihn = s_whhg + 24*512;
  u16* s_whhn = s_wihn + 24*512;
  u16* s_we1  = s_whhn + 24*512;            // [8][1024]
  u16* s_wq   = s_we1 + 8*1024;             // [8][1024]
  float* s_g    = (float*)(s_wq + 8*1024);  // staged graph vector
  float* s_nc   = s_g + 512;                // staged ncur (current node, post-GRU_n)
  float* s_curv = s_nc + 512;               // current node vector pre-update
  float* s_h0   = s_curv + 512;             // fresh-node embedding
  float* s_kloc = s_h0 + 512;               // [8][128] transposed k-cache: [dim][node]
  float* s_bihg = s_kloc + 1024;            // [24]
  float* s_bhhg = s_bihg + 24;
  float* s_bihn = s_bhhg + 24;
  float* s_bhhn = s_bihn + 24;
  float* s_be1  = s_bhhn + 24;              // [8]
  float* s_bq   = s_be1 + 8;                // [8]
  float* s_q8   = s_bq + 8;                 // [8]
  float* s_red  = s_q8 + 8;                 // [16]
  u16*   s_gin  = (u16*)(s_red + 16);       // [128][24] gi_n freeze cache (bf16, bias incl.)

  const int b = blockIdx.x, tid = threadIdx.x;
  const int wv = tid >> 6, lane = tid & 63;
  const int d = b*8 + ((wv < 8) ? wv : 0);

  // workspace: tagged u64 atoms
  u64* Xng = (u64*)ws;         // [2][512][2]: per dim {ncur, g} adjacent (same cache line)
  u64* Xh  = Xng + 2048;       // [512] h0 broadcast
  u64* XE  = Xh + 512;         // [4][64] edge-logit partials (2xbf16)
  u64* XP  = XE + 256;         // [4][64][64] dest-logit partials
  u64* XS  = XP + 16384;       // [4][64] dest half-sums
  u64* XN  = XS + 256;         // [64] final nll pieces

  // ---------------- init: biases + packed bf16 weight slices ----------------
  if (tid < 24){
    int ld = tid/3, gt = tid%3;
    int row = gt*512 + b*8 + ld;
    s_bihg[tid] = bih_g[row]; s_bhhg[tid] = bhh_g[row];
    s_bihn[tid] = bih_n[row]; s_bhhn[tid] = bhh_n[row];
  }
  if (tid < 8){ s_be1[tid] = b_e1[b*8+tid]; s_bq[tid] = b_q[b*8+tid]; }

  for (int r = wv; r < 24; r += 9){           // all 9 waves pack
    int ld = r/3, gt = r%3;
    long grow = (long)(gt*512 + b*8 + ld) * 512;
    float4 a0, a1;
    a0 = *(const float4*)&wih_g[grow + lane*8]; a1 = *(const float4*)&wih_g[grow + lane*8 + 4];
    *(uint4*)&s_wihg[r*512 + lane*8] = pk8(a0, a1);
    a0 = *(const float4*)&whh_g[grow + lane*8]; a1 = *(const float4*)&whh_g[grow + lane*8 + 4];
    *(uint4*)&s_whhg[r*512 + lane*8] = pk8(a0, a1);
    a0 = *(const float4*)&wih_n[grow + lane*8]; a1 = *(const float4*)&wih_n[grow + lane*8 + 4];
    *(uint4*)&s_wihn[r*512 + lane*8] = pk8(a0, a1);
    a0 = *(const float4*)&whh_n[grow + lane*8]; a1 = *(const float4*)&whh_n[grow + lane*8 + 4];
    *(uint4*)&s_whhn[r*512 + lane*8] = pk8(a0, a1);
  }
  if (wv < 8){
    long grow = (long)(b*8 + wv) * 1024;
    #pragma unroll
    for (int h = 0; h < 2; ++h){
      float4 a0 = *(const float4*)&w_e1[grow + h*512 + lane*8];
      float4 a1 = *(const float4*)&w_e1[grow + h*512 + lane*8 + 4];
      *(uint4*)&s_we1[wv*1024 + h*512 + lane*8] = pk8(a0, a1);
      float4 q0 = *(const float4*)&w_q[grow + h*512 + lane*8];
      float4 q1 = *(const float4*)&w_q[grow + h*512 + lane*8 + 4];
      *(uint4*)&s_wq[wv*1024 + h*512 + lane*8] = pk8(q0, q1);
    }
  }
  float we2_0 = w_e2[d], we2_1 = w_e2[512+d];
  float be2_0 = b_e2[0], be2_1 = b_e2[1];
  float nllw = 0.f, sA0 = 0.f, sA1 = 0.f;

  // job state
  int aeV=0, aeSlot=0, aeSel=0, aeOwn=0; u32 aeTag=0;
  int dAV=0, dASlot=0, dAo1=0, dAo2=0, dAcur=0, dAarg=0; u32 dATag=0;
  int dBV=0, dBSlot=0, dBo1=0, dBcur=0, dBarg=0; u32 dBTag=0;
  int ecnt=0, dcnt=0;

  // ---------------- INIT (tag 1): broadcast h0 ----------------
  if (tid < 512) s_g[tid] = node_init[tid];
  __syncthreads();
  // register-cache per-wave bias constants
  float cbg_r=0,cbg_z=0,bg_ni=0,bg_nh=0, bh_gr=0,bh_gz=0;
  float bn_r=0,bn_z=0,bn_nh=0, fb_r=0,fb_z=0,fb_n=0, be1w=0,bqw=0;
  if (wv < 8){
    cbg_r = s_bihg[wv*3+0]+s_bhhg[wv*3+0];
    cbg_z = s_bihg[wv*3+1]+s_bhhg[wv*3+1];
    bg_ni = s_bihg[wv*3+2]; bg_nh = s_bhhg[wv*3+2];
    bh_gr = s_bhhg[wv*3+0]; bh_gz = s_bhhg[wv*3+1];
    bn_r = s_bhhn[wv*3+0]; bn_z = s_bhhn[wv*3+1]; bn_nh = s_bhhn[wv*3+2];
    fb_r = s_bihn[wv*3+0]; fb_z = s_bihn[wv*3+1]; fb_n = s_bihn[wv*3+2];
    be1w = s_be1[wv]; bqw = s_bq[wv];
    const float* wr = w_nip + (long)d*512;
    float4 wa = *(const float4*)&wr[lane*8], wb2 = *(const float4*)&wr[lane*8+4];
    float4 xa = *(float4*)&s_g[lane*8], xb = *(float4*)&s_g[lane*8+4];
    float h0d = wred(dot4f(wa,xa)+dot4f(wb2,xb)) + b_nip[d];
    if (lane == 0) gst64(&Xh[d], (1ull<<32) | f2u(h0d));
  }
  u32 ph = 2;

  float gi0r=0,gi0z=0,gi0n=0, ghn0r=0,ghn0z=0,ghn0n=0;  // caches of *@h0
  int cur = -1, have_se = 0;
  bool first_an = true;

  // ---------------- main sequential scan ----------------
  for (int t = 0; t < LSEQ; ++t){
    int a = actions[t];
    if (a == 1) continue;                    // ADD_EDGE fused into its CD phase
    if (a == 3){ have_se = 1; continue; }    // STOP_EDGE fused into next AN / drain
    if (a < 0 || a >= 4) continue;

    int t1 = (t+1 < LSEQ) ? actions[t+1] : -1;
    int nxt = (t1 == 1);
    int i2 = (t+2 < LSEQ) ? t+2 : LSEQ-1;
    int chn = nxt ? argseq[i2] : 0;          // lookahead: next edge's destination

    if (a == 0){ // ======== ADD_NODE (1 phase; absorbs pending STOP_EDGE) ========
      int eslot = ecnt & 3;
      u32 tg = ph-1; int par = tg & 1;
      if (first_an){
        if (tid < 512){ u64 v = pollt(&Xh[tid], 1u); s_h0[tid] = u2f((u32)v); s_g[tid] = graph0[tid]; }
      } else {
        if (tid < 512){ u64 v = pollt(&Xng[(par*512+tid)*2+1], tg); s_g[tid] = u2f((u32)v); }
      }
      __syncthreads();
      RUN_JOBS();
      if (wv < 8){
        float4 xg_a = *(float4*)&s_g[lane*8], xg_b = *(float4*)&s_g[lane*8+4];
        float4 xc_a = *(float4*)&s_curv[lane*8], xc_b = *(float4*)&s_curv[lane*8+4];
        const u32* Whg = (const u32*)s_whhg;
        if (first_an){
          float4 xh_a = *(float4*)&s_h0[lane*8], xh_b = *(float4*)&s_h0[lane*8+4];
          const u32* Wig = (const u32*)s_wihg; const u32* Wn = (const u32*)s_whhn;
          gi0r = wred(dot8p(*(const uint4*)&Wig[(wv*3+0)*256+lane*4], xh_a,xh_b)) + s_bihg[wv*3+0];
          gi0z = wred(dot8p(*(const uint4*)&Wig[(wv*3+1)*256+lane*4], xh_a,xh_b)) + s_bihg[wv*3+1];
          gi0n = wred(dot8p(*(const uint4*)&Wig[(wv*3+2)*256+lane*4], xh_a,xh_b)) + s_bihg[wv*3+2];
          ghn0r = wred(dot8p(*(const uint4*)&Wn[(wv*3+0)*256+lane*4], xh_a,xh_b)) + bn_r;
          ghn0z = wred(dot8p(*(const uint4*)&Wn[(wv*3+1)*256+lane*4], xh_a,xh_b)) + bn_z;
          ghn0n = wred(dot8p(*(const uint4*)&Wn[(wv*3+2)*256+lane*4], xh_a,xh_b)) + bn_nh;
        }
        { // g' = GRU_g(h0, g) : gi cached
          float ghr = wred(dot8p(*(const uint4*)&Whg[(wv*3+0)*256+lane*4], xg_a,xg_b)) + bh_gr;
          float ghz = wred(dot8p(*(const uint4*)&Whg[(wv*3+1)*256+lane*4], xg_a,xg_b)) + bh_gz;
          float ghn = wred(dot8p(*(const uint4*)&Whg[(wv*3+2)*256+lane*4], xg_a,xg_b)) + bg_nh;
          float r_ = sigm(gi0r + ghr), z_ = sigm(gi0z + ghz);
          float n_ = tanhf(gi0n + r_*ghn);
          if (lane == 0) gst64(&Xng[((ph&1)*512+d)*2+1], ((u64)ph<<32) | f2u((1.f-z_)*n_ + z_*s_g[d]));
        }
        if (nxt){ // fire ncur1 = GRU_n(chosen1, h0) entirely from caches
          float gr = bf2f(s_gin[chn*24+wv*3+0]), gz = bf2f(s_gin[chn*24+wv*3+1]), gn = bf2f(s_gin[chn*24+wv*3+2]);
          float r2 = sigm(gr + ghn0r), z2 = sigm(gz + ghn0z);
          float n2 = tanhf(gn + r2*ghn0n);
          if (lane == 0) gst64(&Xng[((ph&1)*512+d)*2], ((u64)ph<<32) | f2u((1.f-z2)*n2 + z2*s_h0[d]));
        }
        if (cur >= 0){ // freeze prev node: gi_n row + k slice (block-local caches)
          const u32* Win = (const u32*)s_wihn;
          float fr = wred(dot8p(*(const uint4*)&Win[(wv*3+0)*256+lane*4], xc_a,xc_b)) + fb_r;
          float fz = wred(dot8p(*(const uint4*)&Win[(wv*3+1)*256+lane*4], xc_a,xc_b)) + fb_z;
          float fn = wred(dot8p(*(const uint4*)&Win[(wv*3+2)*256+lane*4], xc_a,xc_b)) + fb_n;
          const float* wkr = w_k + (long)d*512;
          float4 ka = *(const float4*)&wkr[lane*8], kb2 = *(const float4*)&wkr[lane*8+4];
          float kv = wred(dot4f(ka,xc_a)+dot4f(kb2,xc_b));
          if (lane == 0){
            s_gin[cur*24+wv*3+0] = f2bf(fr); s_gin[cur*24+wv*3+1] = f2bf(fz); s_gin[cur*24+wv*3+2] = f2bf(fn);
            s_kloc[wv*128 + cur] = kv;
          }
        }
        if (have_se){ // deferred STOP_EDGE e-logit partials
          const u32* Re = (const u32*)s_we1 + wv*512;
          float pe = dot8p(*(const uint4*)&Re[lane*4], xg_a,xg_b) + dot8p(*(const uint4*)&Re[256+lane*4], xc_a,xc_b);
          float hv = fmaxf(wred(pe) + be1w, 0.f);
          if (lane == 0){ s_red[wv*2] = hv*we2_0; s_red[wv*2+1] = hv*we2_1; }
        }
      }
      __syncthreads();
      if (have_se && tid == 0){
        float p0 = 0.f, p1 = 0.f;
        #pragma unroll
        for (int i = 0; i < 8; ++i){ p0 += s_red[i*2]; p1 += s_red[i*2+1]; }
        gst64(&XE[eslot*64 + b], ((u64)ph<<32) | (u32)f2bf(p0) | ((u32)f2bf(p1)<<16));
      }
      if (tid < 512) s_curv[tid] = s_h0[tid];
      SHIFT_JOBS();
      if (have_se){ aeV=1; aeSlot=eslot; aeSel=1; aeOwn=ecnt&63; aeTag=ph; ecnt++; }
      have_se = 0; first_an = false;
      cur += 1; ph += 1;
    }
    else { // ======== CHOOSE_DEST: ONE phase (AE fused; ncur pipelined ahead) ========
      int arg = argseq[t];
      int eslot = ecnt & 3, dslot = dcnt & 3;
      u32 tg = ph-1; int par = tg & 1;
      if (tid < 512){
        u64 v0, v1; int n = 0;
        const u64* p = &Xng[(par*512 + tid)*2];
        do { v0 = gld64(p); v1 = gld64(p+1); }
        while ((((u32)(v0>>32) != tg) || ((u32)(v1>>32) != tg)) && ++n < (1<<20));
        s_nc[tid] = u2f((u32)v0); s_g[tid] = u2f((u32)v1);
      }
      __syncthreads();
      RUN_JOBS();
      if (wv < 8){
        float4 xn_a = *(float4*)&s_nc[lane*8], xn_b = *(float4*)&s_nc[lane*8+4];
        float4 xg_a = *(float4*)&s_g[lane*8],  xg_b = *(float4*)&s_g[lane*8+4];
        float4 xc_a = *(float4*)&s_curv[lane*8], xc_b = *(float4*)&s_curv[lane*8+4];
        const u32* Wn = (const u32*)s_whhn; const u32* Wig = (const u32*)s_wihg; const u32* Whg = (const u32*)s_whhg;
        if (nxt){ // fire ncur_{j+1} = GRU_n(chosen_{j+1}, ncur_j)
          float ghr = wred(dot8p(*(const uint4*)&Wn[(wv*3+0)*256+lane*4], xn_a,xn_b)) + bn_r;
          float ghz = wred(dot8p(*(const uint4*)&Wn[(wv*3+1)*256+lane*4], xn_a,xn_b)) + bn_z;
          float ghn = wred(dot8p(*(const uint4*)&Wn[(wv*3+2)*256+lane*4], xn_a,xn_b)) + bn_nh;
          float gr = bf2f(s_gin[chn*24+wv*3+0]), gz = bf2f(s_gin[chn*24+wv*3+1]), gn = bf2f(s_gin[chn*24+wv*3+2]);
          float r_ = sigm(gr+ghr), z_ = sigm(gz+ghz);
          float n_ = tanhf(gn + r_*ghn);
          if (lane == 0) gst64(&Xng[((ph&1)*512+d)*2], ((u64)ph<<32) | f2u((1.f-z_)*n_ + z_*s_nc[d]));
        }
        { // fire g_j = GRU_g(ncur_j, g_{j-1}); r/z partials combined pre-reduction
          float pr = dot8p(*(const uint4*)&Wig[(wv*3+0)*256+lane*4], xn_a,xn_b)
                   + dot8p(*(const uint4*)&Whg[(wv*3+0)*256+lane*4], xg_a,xg_b);
          float pz = dot8p(*(const uint4*)&Wig[(wv*3+1)*256+lane*4], xn_a,xn_b)
                   + dot8p(*(const uint4*)&Whg[(wv*3+1)*256+lane*4], xg_a,xg_b);
          float r_ = sigm(wred(pr) + cbg_r);
          float z_ = sigm(wred(pz) + cbg_z);
          float gin_ = wred(dot8p(*(const uint4*)&Wig[(wv*3+2)*256+lane*4], xn_a,xn_b)) + bg_ni;
          float ghn_ = wred(dot8p(*(const uint4*)&Whg[(wv*3+2)*256+lane*4], xg_a,xg_b)) + bg_nh;
          float n_ = tanhf(gin_ + r_*ghn_);
          if (lane == 0) gst64(&Xng[((ph&1)*512+d)*2+1], ((u64)ph<<32) | f2u((1.f-z_)*n_ + z_*s_g[d]));
        }
        { // q_j and AE e-logit partials from (g_{j-1}, curv_{j-1})
          const u32* Rq = (const u32*)s_wq + wv*512;
          float pq = dot8p(*(const uint4*)&Rq[lane*4], xg_a,xg_b) + dot8p(*(const uint4*)&Rq[256+lane*4], xc_a,xc_b);
          float qd = wred(pq) + bqw;
          const u32* Re = (const u32*)s_we1 + wv*512;
          float pe = dot8p(*(const uint4*)&Re[lane*4], xg_a,xg_b) + dot8p(*(const uint4*)&Re[256+lane*4], xc_a,xc_b);
          float hv = fmaxf(wred(pe) + be1w, 0.f);
          if (lane == 0){ s_q8[wv] = qd; s_red[wv*2] = hv*we2_0; s_red[wv*2+1] = hv*we2_1; }
        }
      }
      __syncthreads();
      if (tid < 64){ // dest-logit partials: local k slices x local q dims
        float pl0 = 0.f, pl1 = 0.f;
        #pragma unroll
        for (int k = 0; k < 8; ++k){
          pl0 += s_kloc[k*128 + tid]      * s_q8[k];
          pl1 += s_kloc[k*128 + tid + 64] * s_q8[k];
        }
        gst64(&XP[((size_t)(dslot*64 + tid))*64 + b], ((u64)ph<<32) | (u32)f2bf(pl0) | ((u32)f2bf(pl1)<<16));
      }
      if (tid == 64){
        float p0 = 0.f, p1 = 0.f;
        #pragma unroll
        for (int i = 0; i < 8; ++i){ p0 += s_red[i*2]; p1 += s_red[i*2+1]; }
        gst64(&XE[eslot*64 + b], ((u64)ph<<32) | (u32)f2bf(p0) | ((u32)f2bf(p1)<<16));
      }
      if (tid < 512) s_curv[tid] = s_nc[tid];
      SHIFT_JOBS();
      aeV=1; aeSlot=eslot; aeSel=0; aeOwn=ecnt&63; aeTag=ph; ecnt++;
      dAV=1; dASlot=dslot; dAo1=(2*dcnt)&63; dAo2=(2*dcnt+1)&63; dAcur=cur; dAarg=arg; dATag=ph;
      dcnt++;
      ph += 1;
    }
  }

  // ---------------- drain ----------------
  {
    int eslot = ecnt & 3;
    u32 tg = ph-1; int par = tg & 1;
    if (tid < 512){ u64 v = pollt(&Xng[(par*512+tid)*2+1], tg); s_g[tid] = u2f((u32)v); }
    __syncthreads();
    RUN_JOBS();                               // jobs due this phase
    if (have_se && wv < 8){
      float4 xg_a = *(float4*)&s_g[lane*8], xg_b = *(float4*)&s_g[lane*8+4];
      float4 xc_a = *(float4*)&s_curv[lane*8], xc_b = *(float4*)&s_curv[lane*8+4];
      const u32* Re = (const u32*)s_we1 + wv*512;
      float pe = dot8p(*(const uint4*)&Re[lane*4], xg_a,xg_b) + dot8p(*(const uint4*)&Re[256+lane*4], xc_a,xc_b);
      float hv = fmaxf(wred(pe) + be1w, 0.f);
      if (lane == 0){ s_red[wv*2] = hv*we2_0; s_red[wv*2+1] = hv*we2_1; }
    }
    __syncthreads();
    if (have_se && tid == 0){
      float p0 = 0.f, p1 = 0.f;
      #pragma unroll
      for (int i = 0; i < 8; ++i){ p0 += s_red[i*2]; p1 += s_red[i*2+1]; }
      gst64(&XE[eslot*64 + b], ((u64)ph<<32) | (u32)f2bf(p0) | ((u32)f2bf(p1)<<16));
    }
    SHIFT_JOBS();
    RUN_JOBS();                               // stage-B of the last CHOOSE_DEST
    if (wv == 8){
      if (have_se && b == 0){
        u64 v = pollt(&XE[eslot*64 + lane], ph);
        float p0 = wredsh(bf2f((u16)(v & 0xffff)));
        float p1 = wredsh(bf2f((u16)((v>>16) & 0xffff)));
        if (lane == 0){
          float l0 = p0 + be2_0, l1 = p1 + be2_1;
          float m = fmaxf(l0, l1);
          nllw += m + logf(__expf(l0-m) + __expf(l1-m)) - l1;   // STOP_EDGE selects idx 1
        }
      }
      if (lane == 0) gst64(&XN[b], (0xFFFFull<<32) | f2u(nllw));
      if (b == 0){
        u64 v = pollt(&XN[lane], 0xFFFFu);
        float tot = wredsh(u2f((u32)v));
        if (lane == 0) out[0] = tot;
      }
    }
  }
}

extern "C" void kernel_launch(void* const* d_in, const int* in_sizes, int n_in,
                              void* d_out, int out_size, void* d_ws, size_t ws_size,
                              hipStream_t stream) {
  (void)in_sizes; (void)n_in; (void)out_size; (void)ws_size;
  // zero all tag-atom regions (19520 u64) — exact-match tags then poison/replay-safe
  hipMemsetAsync(d_ws, 0, 156160, stream);
  hipFuncSetAttribute((const void*)dgmg_kernel,
                      hipFuncAttributeMaxDynamicSharedMemorySize, SMEM_BYTES);
  dgmg_kernel<<<NBLK, NTHR, SMEM_BYTES, stream>>>(
      (const int*)d_in[0], (const int*)d_in[1],
      (const float*)d_in[2], (const float*)d_in[3], (const float*)d_in[4],
      (const float*)d_in[5], (const float*)d_in[6],
      (const float*)d_in[7], (const float*)d_in[8],
      (const float*)d_in[9], (const float*)d_in[10],
      (const float*)d_in[11],                      /* w_k ; b_k unused (cancels) */
      (const float*)d_in[13], (const float*)d_in[14],
      (const float*)d_in[15], (const float*)d_in[16],
      (const float*)d_in[17], (const float*)d_in[18],
      (const float*)d_in[19], (const float*)d_in[20],
      (const float*)d_in[21],
      (float*)d_out, (unsigned char*)d_ws);
}